// Round 9
// baseline (647.973 us; speedup 1.0000x reference)
//
#include <hip/hip_runtime.h>
#include <hip/hip_bf16.h>
#include <math.h>

#define F_IN   128
#define HID    128
#define NLAYER 3
#define NCLS   40
#define DCAT   512   // F_IN + NLAYER*HID
#define OOUT   64    // padded out-layer cols

typedef short s16x8 __attribute__((ext_vector_type(8)));
typedef unsigned short u16x8 __attribute__((ext_vector_type(8)));
typedef unsigned short u16x4 __attribute__((ext_vector_type(4)));
typedef float f32x4 __attribute__((ext_vector_type(4)));

// ---------------- device helpers ----------------

static __device__ __forceinline__ float silu_f(float x) {
    return x / (1.f + __expf(-x));
}

static __device__ __forceinline__ unsigned short f2bf_rn(float f) {
    union { __hip_bfloat16 h; unsigned short u; } cv;
    cv.h = __float2bfloat16(f);
    return cv.u;
}

static __device__ __forceinline__ void gload_lds16(const void* g, void* l) {
    __builtin_amdgcn_global_load_lds(
        (const __attribute__((address_space(1))) void*)g,
        (__attribute__((address_space(3))) void*)l, 16, 0, 0);
}

// ---------------- graph preprocessing ----------------

__global__ __launch_bounds__(256) void deg_init_kernel(int* deg, int N) {
    for (int i = blockIdx.x * blockDim.x + threadIdx.x; i < N; i += gridDim.x * blockDim.x)
        deg[i] = 1;  // self-loop
}

__global__ __launch_bounds__(256) void deg_count_kernel(const int* __restrict__ dst, int E, int* deg) {
    for (int i = blockIdx.x * blockDim.x + threadIdx.x; i < E; i += gridDim.x * blockDim.x)
        atomicAdd(&deg[dst[i]], 1);
}

__global__ __launch_bounds__(256) void dinv_kernel(const int* __restrict__ deg, float* dinv, int N) {
    for (int i = blockIdx.x * blockDim.x + threadIdx.x; i < N; i += gridDim.x * blockDim.x)
        dinv[i] = rsqrtf((float)deg[i]);
}

// hierarchical scan: 1 elem/thread, 256/block
__global__ __launch_bounds__(256) void scan_reduce_kernel(const int* __restrict__ deg, int* __restrict__ bsum, int N) {
    __shared__ int sh[256];
    int t = threadIdx.x;
    int e = blockIdx.x * 256 + t;
    sh[t] = (e < N) ? deg[e] : 0;
    __syncthreads();
#pragma unroll
    for (int off = 128; off > 0; off >>= 1) {
        if (t < off) sh[t] += sh[t + off];
        __syncthreads();
    }
    if (t == 0) bsum[blockIdx.x] = sh[0];
}

__global__ __launch_bounds__(256) void scan_top_kernel(const int* __restrict__ bsum, int* __restrict__ bbase, int nsb) {
    __shared__ int sh[256];
    int t = threadIdx.x;
    int chunk = (nsb + 255) >> 8;
    int begin = t * chunk;
    int end = begin + chunk; if (end > nsb) end = nsb;
    int s = 0;
    for (int i = begin; i < end; ++i) s += bsum[i];
    sh[t] = s;
    __syncthreads();
#pragma unroll
    for (int off = 1; off < 256; off <<= 1) {
        int v = 0;
        if (t >= off) v = sh[t - off];
        __syncthreads();
        if (t >= off) sh[t] += v;
        __syncthreads();
    }
    int run = (t == 0) ? 0 : sh[t - 1];
    for (int i = begin; i < end; ++i) {
        bbase[i] = run;
        run += bsum[i];
    }
}

__global__ __launch_bounds__(256) void scan_write_kernel(const int* __restrict__ deg,
                                                         const int* __restrict__ bbase,
                                                         int* __restrict__ offs, int* __restrict__ cursor, int N) {
    __shared__ int sh[256];
    int t = threadIdx.x;
    int e = blockIdx.x * 256 + t;
    int d = (e < N) ? deg[e] : 0;
    sh[t] = d;
    __syncthreads();
#pragma unroll
    for (int off = 1; off < 256; off <<= 1) {
        int v = 0;
        if (t >= off) v = sh[t - off];
        __syncthreads();
        if (t >= off) sh[t] += v;
        __syncthreads();
    }
    int incl = sh[t] + bbase[blockIdx.x];
    int excl = incl - d;
    if (e < N) {
        offs[e] = excl;
        cursor[e] = excl;
        if (e == N - 1) offs[N] = incl;
    }
}

__global__ __launch_bounds__(256) void fill_kernel(const int* __restrict__ src, const int* __restrict__ dst,
                                                   int E, int N, int* cursor, int* __restrict__ csr) {
    int total = E + N;
    for (int i = blockIdx.x * blockDim.x + threadIdx.x; i < total; i += gridDim.x * blockDim.x) {
        if (i < E) {
            int d = dst[i];
            int p = atomicAdd(&cursor[d], 1);
            csr[p] = src[i];
        } else {
            int n = i - E;
            int p = atomicAdd(&cursor[n], 1);
            csr[p] = n;
        }
    }
}

// ---------------- weight packing (bf16, MFMA-fragment order) -----------------
// B-fragment for 16x16x32: lane holds W[o = cf*16 + (lane&15)][k = kk*32 + (lane>>4)*8 + e].
// conv: [l][cc(9)][kk(4)][cf(8)][lane(64)][e(8)]
__global__ __launch_bounds__(256) void pack_conv_mfma(const float* __restrict__ bw,
                                                      const float* __restrict__ sw,
                                                      const float* __restrict__ sc,
                                                      unsigned short* __restrict__ wpk) {
    int total = NLAYER * 9 * 4 * 8 * 64 * 8;
    for (int idx = blockIdx.x * blockDim.x + threadIdx.x; idx < total; idx += gridDim.x * blockDim.x) {
        int e    = idx & 7;
        int lane = (idx >> 3) & 63;
        int cf   = (idx >> 9) & 7;
        int kk   = (idx >> 12) & 3;
        int cc   = (idx >> 14) % 9;
        int l    = idx / (9 << 14);
        int o = cf * 16 + (lane & 15);
        int k = kk * 32 + ((lane >> 4) << 3) + e;
        float v;
        if (cc == 8) {                 // silu chunk
            v = bw[(l * 128 + o) * 128 + k];
        } else {                       // spline chunk: 16 feats x 8 bases
            int f = cc * 16 + (k >> 3);
            int j = k & 7;
            int base = (l * 128 + o) * 128 + f;
            v = sw[base * 8 + j] * sc[base];
        }
        wpk[idx] = f2bf_rn(v);
    }
}

// out: [gcc(36)][kk(4)][cf(4)][lane(64)][e(8)], cols >= NCLS zeroed
__global__ __launch_bounds__(256) void pack_out_mfma(const float* __restrict__ bw,
                                                     const float* __restrict__ sw,
                                                     const float* __restrict__ sc,
                                                     unsigned short* __restrict__ wpk) {
    int total = 36 * 4 * 4 * 64 * 8;
    for (int idx = blockIdx.x * blockDim.x + threadIdx.x; idx < total; idx += gridDim.x * blockDim.x) {
        int e    = idx & 7;
        int lane = (idx >> 3) & 63;
        int cf   = (idx >> 9) & 3;
        int kk   = (idx >> 11) & 3;
        int gcc  = idx >> 13;
        int g = gcc / 9, cc = gcc % 9;
        int o = cf * 16 + (lane & 15);
        int k = kk * 32 + ((lane >> 4) << 3) + e;
        float v = 0.f;
        if (o < NCLS) {
            if (cc == 8) {
                int f = g * 128 + k;
                v = bw[o * DCAT + f];
            } else {
                int f = g * 128 + cc * 16 + (k >> 3);
                int j = k & 7;
                int base = o * DCAT + f;
                v = sw[base * 8 + j] * sc[base];
            }
        }
        wpk[idx] = f2bf_rn(v);
    }
}

// ---------------- misc data movement ----------------

__global__ __launch_bounds__(256) void copyx_kernel(const float* __restrict__ x, float* __restrict__ xc, int N) {
    int total = N * F_IN;
    for (int idx = blockIdx.x * blockDim.x + threadIdx.x; idx < total; idx += gridDim.x * blockDim.x) {
        int n = idx >> 7, f = idx & 127;
        xc[(size_t)n * DCAT + f] = x[idx];
    }
}

__global__ __launch_bounds__(512) void affine_init_kernel(float* scA, float* shA) {
    int i = threadIdx.x;
    scA[i] = 1.f; shA[i] = 0.f;
}

// ---------------- fused KAN GEMM + out-layer partial (bf16 MFMA 16x16x32) ----
// Block: 256 threads (4 waves 2x2), tile 128 nodes. LDS = phi only (32KB).
// W (conv 128 cols + out 64 cols) read as per-lane fragments DIRECTLY from
// global (L2-resident, fragment-ordered by pack_*). Chunks 0..7 spline,
// chunk 8 silu staged from silbuf.
template<bool CONV, bool INIT>
__global__ __launch_bounds__(256, 2) void kan_fused_kernel(
    const float* __restrict__ xc, int in_off,
    const float* __restrict__ scA, const float* __restrict__ shA,
    const unsigned short* __restrict__ wconv,
    const unsigned short* __restrict__ wout,
    unsigned short* __restrict__ silbuf,
    unsigned short* __restrict__ htmp,
    const float* __restrict__ dinv,
    float* __restrict__ out_acc, int N) {

    __shared__ __align__(16) char lds_phi[32768];

    const int tid = threadIdx.x;
    const int lane = tid & 63;
    const int wave = tid >> 6;
    const int wr = wave >> 1, wc = wave & 1;
    const int l15 = lane & 15, lg = lane >> 4;
    const int nblk = blockIdx.x * 128;

    const float g0 = -1.f - 3.f * 0.4f;
    const float invh = 1.f / 0.4f;

    // spline staging decomposition: (fg = tid&3 : 4 features), nodes {n0, n0+64}
    const int fg = tid & 3;
    const int n0 = tid >> 2;

    f32x4 accc[4][4];   // conv 128 cols
    f32x4 acco[4][2];   // out 64 cols
    if (CONV) {
#pragma unroll
        for (int r = 0; r < 4; ++r)
#pragma unroll
            for (int c = 0; c < 4; ++c) accc[r][c] = (f32x4)0.f;
    }
#pragma unroll
    for (int r = 0; r < 4; ++r)
#pragma unroll
        for (int c = 0; c < 2; ++c) acco[r][c] = (f32x4)0.f;

    float4 xq[2], scq, shq;
    auto ldx = [&](int cc) {
        int f0 = in_off + cc * 16 + fg * 4;
        scq = *(const float4*)(scA + f0);
        shq = *(const float4*)(shA + f0);
        int gn0 = nblk + n0, gn1 = gn0 + 64;
        xq[0] = (gn0 < N) ? *(const float4*)(xc + (size_t)gn0 * DCAT + f0) : (float4){0.f,0.f,0.f,0.f};
        xq[1] = (gn1 < N) ? *(const float4*)(xc + (size_t)gn1 * DCAT + f0) : (float4){0.f,0.f,0.f,0.f};
    };

    u16x8 pcur[2][4];
    auto phi_compute = [&](int ccc) {
#pragma unroll
        for (int g2 = 0; g2 < 2; ++g2) {
            float xi[4] = {xq[g2].x, xq[g2].y, xq[g2].z, xq[g2].w};
            float scr[4] = {scq.x, scq.y, scq.z, scq.w};
            float shr[4] = {shq.x, shq.y, shq.z, shq.w};
            u16x4 sv;
#pragma unroll
            for (int fl = 0; fl < 4; ++fl) {
                float y = fmaf(xi[fl], scr[fl], shr[fl]);
                sv[fl] = f2bf_rn(silu_f(y));
                float t = (y - g0) * invh;
                float cf = floorf(t);
                int c = (int)cf;
                float u = t - cf;
                float um = 1.f - u;
                float u2 = u * u;
                float um2 = um * um;
                float w0 = um2 * um * (1.f / 6.f);
                float w3 = u2 * u * (1.f / 6.f);
                float w1 = fmaf(fmaf(0.5f, u, -1.f), u2, 2.f / 3.f);
                float w2 = fmaf(fmaf(-0.5f, u, 0.5f), u2, fmaf(0.5f, u, 1.f / 6.f));
                bool e[11];
#pragma unroll
                for (int v = 0; v < 11; ++v) e[v] = (c == v);
#pragma unroll
                for (int s = 0; s < 8; ++s) {
                    float val = 0.f;
                    val = e[s] ? w3 : val;
                    val = e[s + 1] ? w2 : val;
                    val = e[s + 2] ? w1 : val;
                    val = e[s + 3] ? w0 : val;
                    pcur[g2][fl][s] = f2bf_rn(val);
                }
            }
            int gn = nblk + n0 + g2 * 64;
            if (gn < N) {
                int fdst = (ccc * 16 + fg * 4) ^ ((n0 & 7) << 3);
                *(u16x4*)(silbuf + (size_t)gn * 128 + fdst) = sv;
            }
        }
    };

    // wcb/wob: fragment-ordered chunk bases. Per kk: conv cf = wc*4+c, out cf = wc*2+c.
    auto mfma_phase = [&](const unsigned short* wcb, const unsigned short* wob) {
#pragma unroll
        for (int kk = 0; kk < 4; ++kk) {
            const int kb = kk * 64 + lg * 16;
            s16x8 af[4];
#pragma unroll
            for (int r = 0; r < 4; ++r) {
                int n = wr * 64 + r * 16 + l15;
                af[r] = *(const s16x8*)(lds_phi + n * 256 + (kb ^ ((n & 7) << 4)));
            }
            if (CONV) {
#pragma unroll
                for (int c = 0; c < 4; ++c) {
                    int cf = wc * 4 + c;
                    s16x8 b = *(const s16x8*)(wcb + (((size_t)kk * 8 + cf) * 64 + lane) * 8);
#pragma unroll
                    for (int r = 0; r < 4; ++r)
                        accc[r][c] = __builtin_amdgcn_mfma_f32_16x16x32_bf16(af[r], b, accc[r][c], 0, 0, 0);
                }
            }
#pragma unroll
            for (int c = 0; c < 2; ++c) {
                int cf = wc * 2 + c;
                s16x8 b = *(const s16x8*)(wob + (((size_t)kk * 4 + cf) * 64 + lane) * 8);
#pragma unroll
                for (int r = 0; r < 4; ++r)
                    acco[r][c] = __builtin_amdgcn_mfma_f32_16x16x32_bf16(af[r], b, acco[r][c], 0, 0, 0);
            }
        }
    };

    // prologue: chunk 0 phi
    ldx(0);
    phi_compute(0);

    for (int cc = 0; cc < 8; ++cc) {
        __syncthreads();                   // prev MFMA done with phi LDS
        // write phi regs -> LDS
#pragma unroll
        for (int g2 = 0; g2 < 2; ++g2) {
            int n = n0 + g2 * 64;
            int swz = (n & 7) << 4;
#pragma unroll
            for (int i = 0; i < 4; ++i) {
                int byte = n * 256 + ((fg * 64 + i * 16) ^ swz);
                *(u16x8*)(lds_phi + byte) = pcur[g2][i];
            }
        }
        __syncthreads();                   // phi visible
        if (cc < 7) ldx(cc + 1);           // issue next x loads (hidden by MFMA)
        mfma_phase(CONV ? wconv + (size_t)cc * 16384 : nullptr, wout + (size_t)cc * 8192);
        if (cc < 7) phi_compute(cc + 1);   // overlaps MFMA (separate pipes)
    }

    // silu chunk (cc=8): staged back from silbuf, zero VALU
    __syncthreads();                       // prev MFMA done; silbuf stores long drained
    {
        const unsigned short* ssrc = silbuf + (size_t)nblk * 128;
#pragma unroll
        for (int i = 0; i < 8; ++i) {
            int e = tid + i * 256;
            gload_lds16(ssrc + e * 8, lds_phi + e * 16);
        }
    }
    __syncthreads();                       // drains gload_lds
    mfma_phase(CONV ? wconv + (size_t)8 * 16384 : nullptr, wout + (size_t)8 * 8192);

    // epilogue
#pragma unroll
    for (int r = 0; r < 4; ++r) {
        int nb = nblk + wr * 64 + r * 16 + lg * 4;
        if (CONV) {
#pragma unroll
            for (int c = 0; c < 4; ++c) {
                int o = wc * 64 + c * 16 + l15;
#pragma unroll
                for (int q = 0; q < 4; ++q) {
                    int n = nb + q;
                    if (n < N) htmp[(size_t)n * HID + o] = f2bf_rn(accc[r][c][q] * dinv[n]);
                }
            }
        }
#pragma unroll
        for (int c = 0; c < 2; ++c) {
            int o = wc * 32 + c * 16 + l15;
#pragma unroll
            for (int q = 0; q < 4; ++q) {
                int n = nb + q;
                if (n < N) {
                    size_t a = (size_t)n * OOUT + o;
                    float v = acco[r][c][q];
                    if (!INIT) v += out_acc[a];
                    out_acc[a] = v;
                }
            }
        }
    }
}

// ---------------- aggregation (one wave per node; h pre-scaled by dinv) ------
__global__ __launch_bounds__(256) void agg_kernel(const unsigned short* __restrict__ h,
                                                  const float* __restrict__ dinv,
                                                  const int* __restrict__ offs,
                                                  const int* __restrict__ csr,
                                                  const float* __restrict__ bias,
                                                  float* __restrict__ xc, int out_off, int N) {
    int n = blockIdx.x * 4 + (threadIdx.x >> 6);
    if (n >= N) return;
    int lane = threadIdx.x & 63;
    int s = offs[n], e = offs[n + 1];
    float a0 = 0.f, a1 = 0.f, b0 = 0.f, b1 = 0.f;
    float c0 = 0.f, c1 = 0.f, d0 = 0.f, d1 = 0.f;
    int i = s;
    for (; i + 4 <= e; i += 4) {
        int v0 = csr[i], v1 = csr[i + 1], v2 = csr[i + 2], v3 = csr[i + 3];
        unsigned u0 = *(const unsigned*)(h + (size_t)v0 * HID + lane * 2);
        unsigned u1 = *(const unsigned*)(h + (size_t)v1 * HID + lane * 2);
        unsigned u2 = *(const unsigned*)(h + (size_t)v2 * HID + lane * 2);
        unsigned u3 = *(const unsigned*)(h + (size_t)v3 * HID + lane * 2);
        a0 += __uint_as_float(u0 << 16);
        a1 += __uint_as_float(u0 & 0xffff0000u);
        b0 += __uint_as_float(u1 << 16);
        b1 += __uint_as_float(u1 & 0xffff0000u);
        c0 += __uint_as_float(u2 << 16);
        c1 += __uint_as_float(u2 & 0xffff0000u);
        d0 += __uint_as_float(u3 << 16);
        d1 += __uint_as_float(u3 & 0xffff0000u);
    }
    for (; i < e; ++i) {
        int v = csr[i];
        unsigned u = *(const unsigned*)(h + (size_t)v * HID + lane * 2);
        a0 += __uint_as_float(u << 16);
        a1 += __uint_as_float(u & 0xffff0000u);
    }
    a0 += b0 + c0 + d0;
    a1 += b1 + c1 + d1;
    float dn = dinv[n];
    float2 bv = *(const float2*)(bias + lane * 2);
    float2 res = {fmaf(a0, dn, bv.x), fmaf(a1, dn, bv.y)};
    *(float2*)(xc + (size_t)n * DCAT + out_off + lane * 2) = res;
}

// ---------------- batchnorm stats + deferred affine ----------------
__global__ __launch_bounds__(128) void bn_stats_kernel(const float* __restrict__ xc, int off, int N,
                                                       float* __restrict__ bnsum, float* __restrict__ bnsq) {
    int f = threadIdx.x;
    float s = 0.f, q = 0.f;
    for (int n = blockIdx.x; n < N; n += gridDim.x) {
        float v = xc[(size_t)n * DCAT + off + f];
        s += v;
        q += v * v;
    }
    atomicAdd(&bnsum[f], s);
    atomicAdd(&bnsq[f], q);
}

__global__ __launch_bounds__(128) void bn_affine_kernel(const float* __restrict__ bnsum,
                                                        const float* __restrict__ bnsq,
                                                        const float* __restrict__ gamma,
                                                        const float* __restrict__ beta,
                                                        float* scA, float* shA, int seg_off, float invN) {
    int f = threadIdx.x;
    float mu = bnsum[f] * invN;
    float var = bnsq[f] * invN - mu * mu;
    float rs = rsqrtf(var + 1e-5f);
    float s = gamma[f] * rs;
    scA[seg_off + f] = s;
    shA[seg_off + f] = fmaf(-mu, s, beta[f]);
}

// ---------------- log_softmax (thread per node; reads out_acc ld=64) ---------
__global__ __launch_bounds__(256) void logsoftmax_kernel(const float* __restrict__ oacc,
                                                         float* __restrict__ out, int N) {
    for (int n = blockIdx.x * blockDim.x + threadIdx.x; n < N; n += gridDim.x * blockDim.x) {
        const float* row = oacc + (size_t)n * OOUT;
        float m = -1e30f;
#pragma unroll
        for (int j = 0; j < NCLS; ++j) m = fmaxf(m, row[j]);
        float s = 0.f;
#pragma unroll
        for (int j = 0; j < NCLS; ++j) s += __expf(row[j] - m);
        float lse = m + __logf(s);
        float* orow = out + (size_t)n * NCLS;
#pragma unroll
        for (int j = 0; j < NCLS; ++j) orow[j] = row[j] - lse;
    }
}

// ---------------- launch ----------------

extern "C" void kernel_launch(void* const* d_in, const int* in_sizes, int n_in,
                              void* d_out, int out_size, void* d_ws, size_t ws_size,
                              hipStream_t stream) {
    const float* x            = (const float*)d_in[0];
    const int*   eidx         = (const int*)d_in[1];
    const float* conv_base_w  = (const float*)d_in[3];
    const float* conv_spline_w= (const float*)d_in[4];
    const float* conv_scaler  = (const float*)d_in[5];
    const float* conv_bias    = (const float*)d_in[6];
    const float* bn_gamma     = (const float*)d_in[7];
    const float* bn_beta      = (const float*)d_in[8];
    const float* out_base_w   = (const float*)d_in[10];
    const float* out_spline_w = (const float*)d_in[11];
    const float* out_scaler   = (const float*)d_in[12];
    float* out = (float*)d_out;

    int N = in_sizes[0] / F_IN;
    int E = in_sizes[1] / 2;
    const int* esrc = eidx;
    const int* edst = eidx + E;

    int blocks = (N + 127) / 128;
    int npad = blocks * 128;
    int nsb = (N + 255) / 256;

    char* p = (char*)d_ws;
    auto carve = [&](size_t bytes) {
        char* r = p;
        p += (bytes + 255) & ~(size_t)255;
        return r;
    };
    float* xc   = (float*)carve((size_t)N * DCAT * 4);
    unsigned short* htmp = (unsigned short*)carve((size_t)npad * HID * 2);
    float* oacc = (float*)carve((size_t)npad * OOUT * 4);
    unsigned short* silbuf = (unsigned short*)carve((size_t)npad * 128 * 2);
    float* dinv = (float*)carve((size_t)N * 4);
    float* bn   = (float*)carve((size_t)NLAYER * 2 * HID * 4);
    float* scA  = (float*)carve((size_t)DCAT * 4);
    float* shA  = (float*)carve((size_t)DCAT * 4);
    unsigned short* wpkc = (unsigned short*)carve((size_t)NLAYER * 9 * 128 * 128 * 2);
    unsigned short* wpko = (unsigned short*)carve((size_t)36 * 64 * 128 * 2);
    int* deg    = (int*)carve((size_t)N * 4);
    int* offs   = (int*)carve((size_t)(N + 1) * 4);
    int* cursor = (int*)carve((size_t)(N + 1) * 4);
    int* bsum   = (int*)carve((size_t)nsb * 4);
    int* bbase  = (int*)carve((size_t)nsb * 4);
    int* csr    = (int*)carve((size_t)(E + N) * 4);

    hipMemsetAsync(bn, 0, NLAYER * 2 * HID * 4, stream);

    // graph preprocessing
    deg_init_kernel<<<512, 256, 0, stream>>>(deg, N);
    deg_count_kernel<<<1024, 256, 0, stream>>>(edst, E, deg);
    dinv_kernel<<<512, 256, 0, stream>>>(deg, dinv, N);
    scan_reduce_kernel<<<nsb, 256, 0, stream>>>(deg, bsum, N);
    scan_top_kernel<<<1, 256, 0, stream>>>(bsum, bbase, nsb);
    scan_write_kernel<<<nsb, 256, 0, stream>>>(deg, bbase, offs, cursor, N);
    fill_kernel<<<1024, 256, 0, stream>>>(esrc, edst, E, N, cursor, csr);

    // weight packing + x copy + affine init
    pack_conv_mfma<<<1024, 256, 0, stream>>>(conv_base_w, conv_spline_w, conv_scaler, wpkc);
    pack_out_mfma<<<1024, 256, 0, stream>>>(out_base_w, out_spline_w, out_scaler, wpko);
    copyx_kernel<<<2048, 256, 0, stream>>>(x, xc, N);
    affine_init_kernel<<<1, 512, 0, stream>>>(scA, shA);

    float invN = 1.f / (float)N;
    for (int l = 0; l < NLAYER; ++l) {
        int in_off = l * HID;
        int out_off = (l + 1) * HID;
        const unsigned short* wl = wpkc + (size_t)l * 9 * 16384;
        const unsigned short* wo = wpko + (size_t)l * 9 * 8192;
        if (l == 0)
            kan_fused_kernel<true, true><<<blocks, 256, 0, stream>>>(
                xc, in_off, scA, shA, wl, wo, silbuf, htmp, dinv, oacc, N);
        else
            kan_fused_kernel<true, false><<<blocks, 256, 0, stream>>>(
                xc, in_off, scA, shA, wl, wo, silbuf, htmp, dinv, oacc, N);
        agg_kernel<<<(N + 3) / 4, 256, 0, stream>>>(htmp, dinv, offs, csr, conv_bias + l * HID, xc, out_off, N);
        float* bnsum = bn + l * 2 * HID;
        float* bnsq  = bnsum + HID;
        bn_stats_kernel<<<256, 128, 0, stream>>>(xc, out_off, N, bnsum, bnsq);
        bn_affine_kernel<<<1, 128, 0, stream>>>(bnsum, bnsq, bn_gamma + l * HID, bn_beta + l * HID,
                                                scA, shA, out_off, invN);
    }

    // segment 3 (final BN output) -> out partial
    kan_fused_kernel<false, false><<<blocks, 256, 0, stream>>>(
        xc, 384, scA, shA, nullptr, wpko + (size_t)3 * 9 * 8192, silbuf, nullptr, dinv, oacc, N);

    logsoftmax_kernel<<<(N + 255) / 256, 256, 0, stream>>>(oacc, out, N);
}

// Round 10
// 590.840 us; speedup vs baseline: 1.0967x; 1.0967x over previous
//
#include <hip/hip_runtime.h>
#include <hip/hip_bf16.h>
#include <math.h>

#define F_IN   128
#define HID    128
#define NLAYER 3
#define NCLS   40
#define DCAT   512   // F_IN + NLAYER*HID
#define OOUT   64    // padded out-layer cols

typedef short s16x8 __attribute__((ext_vector_type(8)));
typedef unsigned short u16x8 __attribute__((ext_vector_type(8)));
typedef unsigned short u16x4 __attribute__((ext_vector_type(4)));
typedef float f32x4 __attribute__((ext_vector_type(4)));

// ---------------- device helpers ----------------

static __device__ __forceinline__ float silu_f(float x) {
    return x / (1.f + __expf(-x));
}

static __device__ __forceinline__ unsigned short f2bf_rn(float f) {
    union { __hip_bfloat16 h; unsigned short u; } cv;
    cv.h = __float2bfloat16(f);
    return cv.u;
}

static __device__ __forceinline__ void gload_lds16(const void* g, void* l) {
    __builtin_amdgcn_global_load_lds(
        (const __attribute__((address_space(1))) void*)g,
        (__attribute__((address_space(3))) void*)l, 16, 0, 0);
}

// ---------------- graph preprocessing ----------------

__global__ __launch_bounds__(256) void deg_init_kernel(int* deg, int N) {
    for (int i = blockIdx.x * blockDim.x + threadIdx.x; i < N; i += gridDim.x * blockDim.x)
        deg[i] = 1;  // self-loop
}

__global__ __launch_bounds__(256) void deg_count_kernel(const int* __restrict__ dst, int E, int* deg) {
    for (int i = blockIdx.x * blockDim.x + threadIdx.x; i < E; i += gridDim.x * blockDim.x)
        atomicAdd(&deg[dst[i]], 1);
}

__global__ __launch_bounds__(256) void dinv_kernel(const int* __restrict__ deg, float* dinv, int N) {
    for (int i = blockIdx.x * blockDim.x + threadIdx.x; i < N; i += gridDim.x * blockDim.x)
        dinv[i] = rsqrtf((float)deg[i]);
}

// hierarchical scan: 1 elem/thread, 256/block
__global__ __launch_bounds__(256) void scan_reduce_kernel(const int* __restrict__ deg, int* __restrict__ bsum, int N) {
    __shared__ int sh[256];
    int t = threadIdx.x;
    int e = blockIdx.x * 256 + t;
    sh[t] = (e < N) ? deg[e] : 0;
    __syncthreads();
#pragma unroll
    for (int off = 128; off > 0; off >>= 1) {
        if (t < off) sh[t] += sh[t + off];
        __syncthreads();
    }
    if (t == 0) bsum[blockIdx.x] = sh[0];
}

__global__ __launch_bounds__(256) void scan_top_kernel(const int* __restrict__ bsum, int* __restrict__ bbase, int nsb) {
    __shared__ int sh[256];
    int t = threadIdx.x;
    int chunk = (nsb + 255) >> 8;
    int begin = t * chunk;
    int end = begin + chunk; if (end > nsb) end = nsb;
    int s = 0;
    for (int i = begin; i < end; ++i) s += bsum[i];
    sh[t] = s;
    __syncthreads();
#pragma unroll
    for (int off = 1; off < 256; off <<= 1) {
        int v = 0;
        if (t >= off) v = sh[t - off];
        __syncthreads();
        if (t >= off) sh[t] += v;
        __syncthreads();
    }
    int run = (t == 0) ? 0 : sh[t - 1];
    for (int i = begin; i < end; ++i) {
        bbase[i] = run;
        run += bsum[i];
    }
}

__global__ __launch_bounds__(256) void scan_write_kernel(const int* __restrict__ deg,
                                                         const int* __restrict__ bbase,
                                                         int* __restrict__ offs, int* __restrict__ cursor, int N) {
    __shared__ int sh[256];
    int t = threadIdx.x;
    int e = blockIdx.x * 256 + t;
    int d = (e < N) ? deg[e] : 0;
    sh[t] = d;
    __syncthreads();
#pragma unroll
    for (int off = 1; off < 256; off <<= 1) {
        int v = 0;
        if (t >= off) v = sh[t - off];
        __syncthreads();
        if (t >= off) sh[t] += v;
        __syncthreads();
    }
    int incl = sh[t] + bbase[blockIdx.x];
    int excl = incl - d;
    if (e < N) {
        offs[e] = excl;
        cursor[e] = excl;
        if (e == N - 1) offs[N] = incl;
    }
}

__global__ __launch_bounds__(256) void fill_kernel(const int* __restrict__ src, const int* __restrict__ dst,
                                                   int E, int N, int* cursor, int* __restrict__ csr) {
    int total = E + N;
    for (int i = blockIdx.x * blockDim.x + threadIdx.x; i < total; i += gridDim.x * blockDim.x) {
        if (i < E) {
            int d = dst[i];
            int p = atomicAdd(&cursor[d], 1);
            csr[p] = src[i];
        } else {
            int n = i - E;
            int p = atomicAdd(&cursor[n], 1);
            csr[p] = n;
        }
    }
}

// ---------------- weight packing (bf16, MFMA-fragment order) -----------------
// B-fragment for 16x16x32: lane holds W[o = cf*16 + (lane&15)][k = kk*32 + (lane>>4)*8 + e].
// conv: [l][cc(9)][kk(4)][cf(8)][lane(64)][e(8)]
__global__ __launch_bounds__(256) void pack_conv_mfma(const float* __restrict__ bw,
                                                      const float* __restrict__ sw,
                                                      const float* __restrict__ sc,
                                                      unsigned short* __restrict__ wpk) {
    int total = NLAYER * 9 * 4 * 8 * 64 * 8;
    for (int idx = blockIdx.x * blockDim.x + threadIdx.x; idx < total; idx += gridDim.x * blockDim.x) {
        int e    = idx & 7;
        int lane = (idx >> 3) & 63;
        int cf   = (idx >> 9) & 7;
        int kk   = (idx >> 12) & 3;
        int cc   = (idx >> 14) % 9;
        int l    = idx / (9 << 14);
        int o = cf * 16 + (lane & 15);
        int k = kk * 32 + ((lane >> 4) << 3) + e;
        float v;
        if (cc == 8) {                 // silu chunk
            v = bw[(l * 128 + o) * 128 + k];
        } else {                       // spline chunk: 16 feats x 8 bases
            int f = cc * 16 + (k >> 3);
            int j = k & 7;
            int base = (l * 128 + o) * 128 + f;
            v = sw[base * 8 + j] * sc[base];
        }
        wpk[idx] = f2bf_rn(v);
    }
}

// out: [gcc(36)][kk(4)][cf(4)][lane(64)][e(8)], cols >= NCLS zeroed
__global__ __launch_bounds__(256) void pack_out_mfma(const float* __restrict__ bw,
                                                     const float* __restrict__ sw,
                                                     const float* __restrict__ sc,
                                                     unsigned short* __restrict__ wpk) {
    int total = 36 * 4 * 4 * 64 * 8;
    for (int idx = blockIdx.x * blockDim.x + threadIdx.x; idx < total; idx += gridDim.x * blockDim.x) {
        int e    = idx & 7;
        int lane = (idx >> 3) & 63;
        int cf   = (idx >> 9) & 3;
        int kk   = (idx >> 11) & 3;
        int gcc  = idx >> 13;
        int g = gcc / 9, cc = gcc % 9;
        int o = cf * 16 + (lane & 15);
        int k = kk * 32 + ((lane >> 4) << 3) + e;
        float v = 0.f;
        if (o < NCLS) {
            if (cc == 8) {
                int f = g * 128 + k;
                v = bw[o * DCAT + f];
            } else {
                int f = g * 128 + cc * 16 + (k >> 3);
                int j = k & 7;
                int base = o * DCAT + f;
                v = sw[base * 8 + j] * sc[base];
            }
        }
        wpk[idx] = f2bf_rn(v);
    }
}

// ---------------- misc data movement ----------------

__global__ __launch_bounds__(256) void copyx_kernel(const float* __restrict__ x, float* __restrict__ xc, int N) {
    int total = N * F_IN;
    for (int idx = blockIdx.x * blockDim.x + threadIdx.x; idx < total; idx += gridDim.x * blockDim.x) {
        int n = idx >> 7, f = idx & 127;
        xc[(size_t)n * DCAT + f] = x[idx];
    }
}

__global__ __launch_bounds__(512) void affine_init_kernel(float* scA, float* shA) {
    int i = threadIdx.x;
    scA[i] = 1.f; shA[i] = 0.f;
}

// ---------------- fused KAN GEMM + out-layer partial (bf16 MFMA 16x16x32) ----
// Block: 256 threads (4 waves), tile 64 nodes -> 782 blocks (~3 blocks/CU).
// Each wave: all 64 rows, conv cols wave*32..+31 (2 frags), out cols wave*16..+15.
// LDS = phi only (16KB). W read as per-lane fragments directly from global
// (L2-resident, fragment-ordered). Chunks 0..7 spline, chunk 8 silu from silbuf.
template<bool CONV, bool INIT>
__global__ __launch_bounds__(256, 3) void kan_fused_kernel(
    const float* __restrict__ xc, int in_off,
    const float* __restrict__ scA, const float* __restrict__ shA,
    const unsigned short* __restrict__ wconv,
    const unsigned short* __restrict__ wout,
    unsigned short* __restrict__ silbuf,
    unsigned short* __restrict__ htmp,
    const float* __restrict__ dinv,
    float* __restrict__ out_acc, int N) {

    __shared__ __align__(16) char lds_phi[16384];

    const int tid = threadIdx.x;
    const int lane = tid & 63;
    const int wave = tid >> 6;
    const int l15 = lane & 15, lg = lane >> 4;
    const int nblk = blockIdx.x * 64;

    const float g0 = -1.f - 3.f * 0.4f;
    const float invh = 1.f / 0.4f;

    // phi staging decomposition: thread -> node n0 = tid>>2, feats fg*4..fg*4+3
    const int fg = tid & 3;
    const int n0 = tid >> 2;   // 0..63

    f32x4 accc[4][2];   // conv: 4 row-tiles x 2 col-frags
    f32x4 acco[4];      // out:  4 row-tiles x 1 col-frag
    if (CONV) {
#pragma unroll
        for (int r = 0; r < 4; ++r)
#pragma unroll
            for (int c = 0; c < 2; ++c) accc[r][c] = (f32x4)0.f;
    }
#pragma unroll
    for (int r = 0; r < 4; ++r) acco[r] = (f32x4)0.f;

    float4 xq, scq, shq;
    auto ldx = [&](int cc) {
        int f0 = in_off + cc * 16 + fg * 4;
        scq = *(const float4*)(scA + f0);
        shq = *(const float4*)(shA + f0);
        int gn = nblk + n0;
        xq = (gn < N) ? *(const float4*)(xc + (size_t)gn * DCAT + f0) : (float4){0.f,0.f,0.f,0.f};
    };

    u16x8 pcur[4];
    auto phi_compute = [&](int ccc) {
        float xi[4] = {xq.x, xq.y, xq.z, xq.w};
        float scr[4] = {scq.x, scq.y, scq.z, scq.w};
        float shr[4] = {shq.x, shq.y, shq.z, shq.w};
        u16x4 sv;
#pragma unroll
        for (int fl = 0; fl < 4; ++fl) {
            float y = fmaf(xi[fl], scr[fl], shr[fl]);
            sv[fl] = f2bf_rn(silu_f(y));
            float t = (y - g0) * invh;
            float cf = floorf(t);
            int c = (int)cf;
            float u = t - cf;
            float um = 1.f - u;
            float u2 = u * u;
            float um2 = um * um;
            float w0 = um2 * um * (1.f / 6.f);
            float w3 = u2 * u * (1.f / 6.f);
            float w1 = fmaf(fmaf(0.5f, u, -1.f), u2, 2.f / 3.f);
            float w2 = fmaf(fmaf(-0.5f, u, 0.5f), u2, fmaf(0.5f, u, 1.f / 6.f));
            bool e[11];
#pragma unroll
            for (int v = 0; v < 11; ++v) e[v] = (c == v);
#pragma unroll
            for (int s = 0; s < 8; ++s) {
                float val = 0.f;
                val = e[s] ? w3 : val;
                val = e[s + 1] ? w2 : val;
                val = e[s + 2] ? w1 : val;
                val = e[s + 3] ? w0 : val;
                pcur[fl][s] = f2bf_rn(val);
            }
        }
        int gn = nblk + n0;
        if (gn < N) {
            int fdst = (ccc * 16 + fg * 4) ^ ((n0 & 7) << 3);
            *(u16x4*)(silbuf + (size_t)gn * 128 + fdst) = sv;
        }
    };

    // wcb/wob: fragment-ordered chunk bases. conv cf = wave*2+c; out cf = wave.
    auto mfma_phase = [&](const unsigned short* wcb, const unsigned short* wob) {
#pragma unroll
        for (int kk = 0; kk < 4; ++kk) {
            const int kb = kk * 64 + lg * 16;
            s16x8 af[4];
#pragma unroll
            for (int r = 0; r < 4; ++r) {
                int n = r * 16 + l15;
                af[r] = *(const s16x8*)(lds_phi + n * 256 + (kb ^ ((n & 7) << 4)));
            }
            if (CONV) {
#pragma unroll
                for (int c = 0; c < 2; ++c) {
                    int cf = wave * 2 + c;
                    s16x8 b = *(const s16x8*)(wcb + (((size_t)kk * 8 + cf) * 64 + lane) * 8);
#pragma unroll
                    for (int r = 0; r < 4; ++r)
                        accc[r][c] = __builtin_amdgcn_mfma_f32_16x16x32_bf16(af[r], b, accc[r][c], 0, 0, 0);
                }
            }
            {
                s16x8 b = *(const s16x8*)(wob + (((size_t)kk * 4 + wave) * 64 + lane) * 8);
#pragma unroll
                for (int r = 0; r < 4; ++r)
                    acco[r] = __builtin_amdgcn_mfma_f32_16x16x32_bf16(af[r], b, acco[r], 0, 0, 0);
            }
        }
    };

    // prologue: chunk 0 phi
    ldx(0);
    phi_compute(0);

    for (int cc = 0; cc < 8; ++cc) {
        __syncthreads();                   // prev MFMA done with phi LDS
        // write phi regs -> LDS (one node x 4 feats = 4 x u16x8)
        {
            int swz = (n0 & 7) << 4;
#pragma unroll
            for (int i = 0; i < 4; ++i) {
                int byte = n0 * 256 + ((fg * 64 + i * 16) ^ swz);
                *(u16x8*)(lds_phi + byte) = pcur[i];
            }
        }
        __syncthreads();                   // phi visible
        if (cc < 7) ldx(cc + 1);           // issue next x loads (hidden by MFMA)
        mfma_phase(CONV ? wconv + (size_t)cc * 16384 : nullptr, wout + (size_t)cc * 8192);
        if (cc < 7) phi_compute(cc + 1);   // overlaps MFMA (separate pipes)
    }

    // silu chunk (cc=8): staged back from silbuf, zero VALU
    __syncthreads();                       // prev MFMA done; silbuf stores long drained
    {
        const unsigned short* ssrc = silbuf + (size_t)nblk * 128;
#pragma unroll
        for (int i = 0; i < 4; ++i) {
            int e = tid + i * 256;
            gload_lds16(ssrc + e * 8, lds_phi + e * 16);
        }
    }
    __syncthreads();                       // drains gload_lds
    mfma_phase(CONV ? wconv + (size_t)8 * 16384 : nullptr, wout + (size_t)8 * 8192);

    // epilogue: C row = r*16 + lg*4 + q, conv col = wave*32 + c*16 + l15, out col = wave*16 + l15
#pragma unroll
    for (int r = 0; r < 4; ++r) {
        int nb = nblk + r * 16 + lg * 4;
        if (CONV) {
#pragma unroll
            for (int c = 0; c < 2; ++c) {
                int o = wave * 32 + c * 16 + l15;
#pragma unroll
                for (int q = 0; q < 4; ++q) {
                    int n = nb + q;
                    if (n < N) htmp[(size_t)n * HID + o] = f2bf_rn(accc[r][c][q] * dinv[n]);
                }
            }
        }
        {
            int o = wave * 16 + l15;
            if (o < NCLS) {
#pragma unroll
                for (int q = 0; q < 4; ++q) {
                    int n = nb + q;
                    if (n < N) {
                        size_t a = (size_t)n * OOUT + o;
                        float v = acco[r][q];
                        if (!INIT) v += out_acc[a];
                        out_acc[a] = v;
                    }
                }
            }
        }
    }
}

// ---------------- aggregation (one wave per node; h pre-scaled by dinv) ------
__global__ __launch_bounds__(256) void agg_kernel(const unsigned short* __restrict__ h,
                                                  const float* __restrict__ dinv,
                                                  const int* __restrict__ offs,
                                                  const int* __restrict__ csr,
                                                  const float* __restrict__ bias,
                                                  float* __restrict__ xc, int out_off, int N) {
    int n = blockIdx.x * 4 + (threadIdx.x >> 6);
    if (n >= N) return;
    int lane = threadIdx.x & 63;
    int s = offs[n], e = offs[n + 1];
    float a0 = 0.f, a1 = 0.f, b0 = 0.f, b1 = 0.f;
    float c0 = 0.f, c1 = 0.f, d0 = 0.f, d1 = 0.f;
    int i = s;
    for (; i + 4 <= e; i += 4) {
        int v0 = csr[i], v1 = csr[i + 1], v2 = csr[i + 2], v3 = csr[i + 3];
        unsigned u0 = *(const unsigned*)(h + (size_t)v0 * HID + lane * 2);
        unsigned u1 = *(const unsigned*)(h + (size_t)v1 * HID + lane * 2);
        unsigned u2 = *(const unsigned*)(h + (size_t)v2 * HID + lane * 2);
        unsigned u3 = *(const unsigned*)(h + (size_t)v3 * HID + lane * 2);
        a0 += __uint_as_float(u0 << 16);
        a1 += __uint_as_float(u0 & 0xffff0000u);
        b0 += __uint_as_float(u1 << 16);
        b1 += __uint_as_float(u1 & 0xffff0000u);
        c0 += __uint_as_float(u2 << 16);
        c1 += __uint_as_float(u2 & 0xffff0000u);
        d0 += __uint_as_float(u3 << 16);
        d1 += __uint_as_float(u3 & 0xffff0000u);
    }
    for (; i < e; ++i) {
        int v = csr[i];
        unsigned u = *(const unsigned*)(h + (size_t)v * HID + lane * 2);
        a0 += __uint_as_float(u << 16);
        a1 += __uint_as_float(u & 0xffff0000u);
    }
    a0 += b0 + c0 + d0;
    a1 += b1 + c1 + d1;
    float dn = dinv[n];
    float2 bv = *(const float2*)(bias + lane * 2);
    float2 res = {fmaf(a0, dn, bv.x), fmaf(a1, dn, bv.y)};
    *(float2*)(xc + (size_t)n * DCAT + out_off + lane * 2) = res;
}

// ---------------- batchnorm stats + deferred affine ----------------
__global__ __launch_bounds__(128) void bn_stats_kernel(const float* __restrict__ xc, int off, int N,
                                                       float* __restrict__ bnsum, float* __restrict__ bnsq) {
    int f = threadIdx.x;
    float s = 0.f, q = 0.f;
    for (int n = blockIdx.x; n < N; n += gridDim.x) {
        float v = xc[(size_t)n * DCAT + off + f];
        s += v;
        q += v * v;
    }
    atomicAdd(&bnsum[f], s);
    atomicAdd(&bnsq[f], q);
}

__global__ __launch_bounds__(128) void bn_affine_kernel(const float* __restrict__ bnsum,
                                                        const float* __restrict__ bnsq,
                                                        const float* __restrict__ gamma,
                                                        const float* __restrict__ beta,
                                                        float* scA, float* shA, int seg_off, float invN) {
    int f = threadIdx.x;
    float mu = bnsum[f] * invN;
    float var = bnsq[f] * invN - mu * mu;
    float rs = rsqrtf(var + 1e-5f);
    float s = gamma[f] * rs;
    scA[seg_off + f] = s;
    shA[seg_off + f] = fmaf(-mu, s, beta[f]);
}

// ---------------- log_softmax (thread per node; reads out_acc ld=64) ---------
__global__ __launch_bounds__(256) void logsoftmax_kernel(const float* __restrict__ oacc,
                                                         float* __restrict__ out, int N) {
    for (int n = blockIdx.x * blockDim.x + threadIdx.x; n < N; n += gridDim.x * blockDim.x) {
        const float* row = oacc + (size_t)n * OOUT;
        float m = -1e30f;
#pragma unroll
        for (int j = 0; j < NCLS; ++j) m = fmaxf(m, row[j]);
        float s = 0.f;
#pragma unroll
        for (int j = 0; j < NCLS; ++j) s += __expf(row[j] - m);
        float lse = m + __logf(s);
        float* orow = out + (size_t)n * NCLS;
#pragma unroll
        for (int j = 0; j < NCLS; ++j) orow[j] = row[j] - lse;
    }
}

// ---------------- launch ----------------

extern "C" void kernel_launch(void* const* d_in, const int* in_sizes, int n_in,
                              void* d_out, int out_size, void* d_ws, size_t ws_size,
                              hipStream_t stream) {
    const float* x            = (const float*)d_in[0];
    const int*   eidx         = (const int*)d_in[1];
    const float* conv_base_w  = (const float*)d_in[3];
    const float* conv_spline_w= (const float*)d_in[4];
    const float* conv_scaler  = (const float*)d_in[5];
    const float* conv_bias    = (const float*)d_in[6];
    const float* bn_gamma     = (const float*)d_in[7];
    const float* bn_beta      = (const float*)d_in[8];
    const float* out_base_w   = (const float*)d_in[10];
    const float* out_spline_w = (const float*)d_in[11];
    const float* out_scaler   = (const float*)d_in[12];
    float* out = (float*)d_out;

    int N = in_sizes[0] / F_IN;
    int E = in_sizes[1] / 2;
    const int* esrc = eidx;
    const int* edst = eidx + E;

    int blocks = (N + 63) / 64;
    int npad = blocks * 64;
    int nsb = (N + 255) / 256;

    char* p = (char*)d_ws;
    auto carve = [&](size_t bytes) {
        char* r = p;
        p += (bytes + 255) & ~(size_t)255;
        return r;
    };
    float* xc   = (float*)carve((size_t)N * DCAT * 4);
    unsigned short* htmp = (unsigned short*)carve((size_t)npad * HID * 2);
    float* oacc = (float*)carve((size_t)npad * OOUT * 4);
    unsigned short* silbuf = (unsigned short*)carve((size_t)npad * 128 * 2);
    float* dinv = (float*)carve((size_t)N * 4);
    float* bn   = (float*)carve((size_t)NLAYER * 2 * HID * 4);
    float* scA  = (float*)carve((size_t)DCAT * 4);
    float* shA  = (float*)carve((size_t)DCAT * 4);
    unsigned short* wpkc = (unsigned short*)carve((size_t)NLAYER * 9 * 128 * 128 * 2);
    unsigned short* wpko = (unsigned short*)carve((size_t)36 * 64 * 128 * 2);
    int* deg    = (int*)carve((size_t)N * 4);
    int* offs   = (int*)carve((size_t)(N + 1) * 4);
    int* cursor = (int*)carve((size_t)(N + 1) * 4);
    int* bsum   = (int*)carve((size_t)nsb * 4);
    int* bbase  = (int*)carve((size_t)nsb * 4);
    int* csr    = (int*)carve((size_t)(E + N) * 4);

    hipMemsetAsync(bn, 0, NLAYER * 2 * HID * 4, stream);

    // graph preprocessing
    deg_init_kernel<<<512, 256, 0, stream>>>(deg, N);
    deg_count_kernel<<<1024, 256, 0, stream>>>(edst, E, deg);
    dinv_kernel<<<512, 256, 0, stream>>>(deg, dinv, N);
    scan_reduce_kernel<<<nsb, 256, 0, stream>>>(deg, bsum, N);
    scan_top_kernel<<<1, 256, 0, stream>>>(bsum, bbase, nsb);
    scan_write_kernel<<<nsb, 256, 0, stream>>>(deg, bbase, offs, cursor, N);
    fill_kernel<<<1024, 256, 0, stream>>>(esrc, edst, E, N, cursor, csr);

    // weight packing + x copy + affine init
    pack_conv_mfma<<<1024, 256, 0, stream>>>(conv_base_w, conv_spline_w, conv_scaler, wpkc);
    pack_out_mfma<<<1024, 256, 0, stream>>>(out_base_w, out_spline_w, out_scaler, wpko);
    copyx_kernel<<<2048, 256, 0, stream>>>(x, xc, N);
    affine_init_kernel<<<1, 512, 0, stream>>>(scA, shA);

    float invN = 1.f / (float)N;
    for (int l = 0; l < NLAYER; ++l) {
        int in_off = l * HID;
        int out_off = (l + 1) * HID;
        const unsigned short* wl = wpkc + (size_t)l * 9 * 16384;
        const unsigned short* wo = wpko + (size_t)l * 9 * 8192;
        if (l == 0)
            kan_fused_kernel<true, true><<<blocks, 256, 0, stream>>>(
                xc, in_off, scA, shA, wl, wo, silbuf, htmp, dinv, oacc, N);
        else
            kan_fused_kernel<true, false><<<blocks, 256, 0, stream>>>(
                xc, in_off, scA, shA, wl, wo, silbuf, htmp, dinv, oacc, N);
        agg_kernel<<<(N + 3) / 4, 256, 0, stream>>>(htmp, dinv, offs, csr, conv_bias + l * HID, xc, out_off, N);
        float* bnsum = bn + l * 2 * HID;
        float* bnsq  = bnsum + HID;
        bn_stats_kernel<<<256, 128, 0, stream>>>(xc, out_off, N, bnsum, bnsq);
        bn_affine_kernel<<<1, 128, 0, stream>>>(bnsum, bnsq, bn_gamma + l * HID, bn_beta + l * HID,
                                                scA, shA, out_off, invN);
    }

    // segment 3 (final BN output) -> out partial
    kan_fused_kernel<false, false><<<blocks, 256, 0, stream>>>(
        xc, 384, scA, shA, nullptr, wpko + (size_t)3 * 9 * 8192, silbuf, nullptr, dinv, oacc, N);

    logsoftmax_kernel<<<(N + 255) / 256, 256, 0, stream>>>(oacc, out, N);
}

// Round 11
// 545.500 us; speedup vs baseline: 1.1878x; 1.0831x over previous
//
#include <hip/hip_runtime.h>
#include <hip/hip_bf16.h>
#include <math.h>

#define F_IN   128
#define HID    128
#define NLAYER 3
#define NCLS   40
#define DCAT   512   // F_IN + NLAYER*HID
#define OOUT   64    // padded out-layer cols

typedef short s16x8 __attribute__((ext_vector_type(8)));
typedef unsigned short u16x8 __attribute__((ext_vector_type(8)));
typedef unsigned short u16x4 __attribute__((ext_vector_type(4)));
typedef float f32x4 __attribute__((ext_vector_type(4)));

// ---------------- device helpers ----------------

static __device__ __forceinline__ float silu_f(float x) {
    return x / (1.f + __expf(-x));
}

static __device__ __forceinline__ unsigned short f2bf_rn(float f) {
    union { __hip_bfloat16 h; unsigned short u; } cv;
    cv.h = __float2bfloat16(f);
    return cv.u;
}

static __device__ __forceinline__ void gload_lds16(const void* g, void* l) {
    __builtin_amdgcn_global_load_lds(
        (const __attribute__((address_space(1))) void*)g,
        (__attribute__((address_space(3))) void*)l, 16, 0, 0);
}

// ---------------- graph preprocessing ----------------

__global__ __launch_bounds__(256) void deg_init_kernel(int* deg, int N) {
    for (int i = blockIdx.x * blockDim.x + threadIdx.x; i < N; i += gridDim.x * blockDim.x)
        deg[i] = 1;  // self-loop
}

__global__ __launch_bounds__(256) void deg_count_kernel(const int* __restrict__ dst, int E, int* deg) {
    for (int i = blockIdx.x * blockDim.x + threadIdx.x; i < E; i += gridDim.x * blockDim.x)
        atomicAdd(&deg[dst[i]], 1);
}

__global__ __launch_bounds__(256) void dinv_kernel(const int* __restrict__ deg, float* dinv, int N) {
    for (int i = blockIdx.x * blockDim.x + threadIdx.x; i < N; i += gridDim.x * blockDim.x)
        dinv[i] = rsqrtf((float)deg[i]);
}

// hierarchical scan: 1 elem/thread, 256/block
__global__ __launch_bounds__(256) void scan_reduce_kernel(const int* __restrict__ deg, int* __restrict__ bsum, int N) {
    __shared__ int sh[256];
    int t = threadIdx.x;
    int e = blockIdx.x * 256 + t;
    sh[t] = (e < N) ? deg[e] : 0;
    __syncthreads();
#pragma unroll
    for (int off = 128; off > 0; off >>= 1) {
        if (t < off) sh[t] += sh[t + off];
        __syncthreads();
    }
    if (t == 0) bsum[blockIdx.x] = sh[0];
}

__global__ __launch_bounds__(256) void scan_top_kernel(const int* __restrict__ bsum, int* __restrict__ bbase, int nsb) {
    __shared__ int sh[256];
    int t = threadIdx.x;
    int chunk = (nsb + 255) >> 8;
    int begin = t * chunk;
    int end = begin + chunk; if (end > nsb) end = nsb;
    int s = 0;
    for (int i = begin; i < end; ++i) s += bsum[i];
    sh[t] = s;
    __syncthreads();
#pragma unroll
    for (int off = 1; off < 256; off <<= 1) {
        int v = 0;
        if (t >= off) v = sh[t - off];
        __syncthreads();
        if (t >= off) sh[t] += v;
        __syncthreads();
    }
    int run = (t == 0) ? 0 : sh[t - 1];
    for (int i = begin; i < end; ++i) {
        bbase[i] = run;
        run += bsum[i];
    }
}

__global__ __launch_bounds__(256) void scan_write_kernel(const int* __restrict__ deg,
                                                         const int* __restrict__ bbase,
                                                         int* __restrict__ offs, int* __restrict__ cursor, int N) {
    __shared__ int sh[256];
    int t = threadIdx.x;
    int e = blockIdx.x * 256 + t;
    int d = (e < N) ? deg[e] : 0;
    sh[t] = d;
    __syncthreads();
#pragma unroll
    for (int off = 1; off < 256; off <<= 1) {
        int v = 0;
        if (t >= off) v = sh[t - off];
        __syncthreads();
        if (t >= off) sh[t] += v;
        __syncthreads();
    }
    int incl = sh[t] + bbase[blockIdx.x];
    int excl = incl - d;
    if (e < N) {
        offs[e] = excl;
        cursor[e] = excl;
        if (e == N - 1) offs[N] = incl;
    }
}

__global__ __launch_bounds__(256) void fill_kernel(const int* __restrict__ src, const int* __restrict__ dst,
                                                   int E, int N, int* cursor, int* __restrict__ csr) {
    int total = E + N;
    for (int i = blockIdx.x * blockDim.x + threadIdx.x; i < total; i += gridDim.x * blockDim.x) {
        if (i < E) {
            int d = dst[i];
            int p = atomicAdd(&cursor[d], 1);
            csr[p] = src[i];
        } else {
            int n = i - E;
            int p = atomicAdd(&cursor[n], 1);
            csr[p] = n;
        }
    }
}

// ---------------- weight packing (bf16, MFMA-fragment order) -----------------
// B-fragment for 16x16x32: lane holds W[o = cf*16 + (lane&15)][k = kk*32 + (lane>>4)*8 + e].
// conv: [l][cc(9)][kk(4)][cf(8)][lane(64)][e(8)]
__global__ __launch_bounds__(256) void pack_conv_mfma(const float* __restrict__ bw,
                                                      const float* __restrict__ sw,
                                                      const float* __restrict__ sc,
                                                      unsigned short* __restrict__ wpk) {
    int total = NLAYER * 9 * 4 * 8 * 64 * 8;
    for (int idx = blockIdx.x * blockDim.x + threadIdx.x; idx < total; idx += gridDim.x * blockDim.x) {
        int e    = idx & 7;
        int lane = (idx >> 3) & 63;
        int cf   = (idx >> 9) & 7;
        int kk   = (idx >> 12) & 3;
        int cc   = (idx >> 14) % 9;
        int l    = idx / (9 << 14);
        int o = cf * 16 + (lane & 15);
        int k = kk * 32 + ((lane >> 4) << 3) + e;
        float v;
        if (cc == 8) {                 // silu chunk
            v = bw[(l * 128 + o) * 128 + k];
        } else {                       // spline chunk: 16 feats x 8 bases
            int f = cc * 16 + (k >> 3);
            int j = k & 7;
            int base = (l * 128 + o) * 128 + f;
            v = sw[base * 8 + j] * sc[base];
        }
        wpk[idx] = f2bf_rn(v);
    }
}

// out: [gcc(36)][kk(4)][cf(4)][lane(64)][e(8)], cols >= NCLS zeroed
__global__ __launch_bounds__(256) void pack_out_mfma(const float* __restrict__ bw,
                                                     const float* __restrict__ sw,
                                                     const float* __restrict__ sc,
                                                     unsigned short* __restrict__ wpk) {
    int total = 36 * 4 * 4 * 64 * 8;
    for (int idx = blockIdx.x * blockDim.x + threadIdx.x; idx < total; idx += gridDim.x * blockDim.x) {
        int e    = idx & 7;
        int lane = (idx >> 3) & 63;
        int cf   = (idx >> 9) & 3;
        int kk   = (idx >> 11) & 3;
        int gcc  = idx >> 13;
        int g = gcc / 9, cc = gcc % 9;
        int o = cf * 16 + (lane & 15);
        int k = kk * 32 + ((lane >> 4) << 3) + e;
        float v = 0.f;
        if (o < NCLS) {
            if (cc == 8) {
                int f = g * 128 + k;
                v = bw[o * DCAT + f];
            } else {
                int f = g * 128 + cc * 16 + (k >> 3);
                int j = k & 7;
                int base = o * DCAT + f;
                v = sw[base * 8 + j] * sc[base];
            }
        }
        wpk[idx] = f2bf_rn(v);
    }
}

// ---------------- misc data movement ----------------

__global__ __launch_bounds__(256) void copyx_kernel(const float* __restrict__ x, float* __restrict__ xc, int N) {
    int total = N * F_IN;
    for (int idx = blockIdx.x * blockDim.x + threadIdx.x; idx < total; idx += gridDim.x * blockDim.x) {
        int n = idx >> 7, f = idx & 127;
        xc[(size_t)n * DCAT + f] = x[idx];
    }
}

__global__ __launch_bounds__(512) void affine_init_kernel(float* scA, float* shA) {
    int i = threadIdx.x;
    scA[i] = 1.f; shA[i] = 0.f;
}

// ---------------- fused KAN GEMM + out-layer partial (bf16 MFMA 16x16x32) ----
// Block: 256 threads (4 waves), tile 64 nodes -> 782 blocks.
// Deep pipeline: phi double-buffered in LDS (ONE barrier/chunk); W fragments
// prefetched into registers one chunk ahead; x prefetched two chunks ahead.
// Chunks 0..7 spline, chunk 8 silu staged from silbuf via global_load_lds.
template<bool CONV, bool INIT>
__global__ __launch_bounds__(256, 2) void kan_fused_kernel(
    const float* __restrict__ xc, int in_off,
    const float* __restrict__ scA, const float* __restrict__ shA,
    const unsigned short* __restrict__ wconv,
    const unsigned short* __restrict__ wout,
    unsigned short* __restrict__ silbuf,
    unsigned short* __restrict__ htmp,
    const float* __restrict__ dinv,
    float* __restrict__ out_acc, int N) {

    __shared__ __align__(16) char lds_phi0[16384];
    __shared__ __align__(16) char lds_phi1[16384];

    const int tid = threadIdx.x;
    const int lane = tid & 63;
    const int wave = tid >> 6;
    const int l15 = lane & 15, lg = lane >> 4;
    const int nblk = blockIdx.x * 64;

    const float g0 = -1.f - 3.f * 0.4f;
    const float invh = 1.f / 0.4f;

    const int fg = tid & 3;
    const int n0 = tid >> 2;   // 0..63

    f32x4 accc[4][2];
    f32x4 acco[4];
    if (CONV) {
#pragma unroll
        for (int r = 0; r < 4; ++r)
#pragma unroll
            for (int c = 0; c < 2; ++c) accc[r][c] = (f32x4)0.f;
    }
#pragma unroll
    for (int r = 0; r < 4; ++r) acco[r] = (f32x4)0.f;

    // double-buffered x/affine (2 chunks ahead)
    float4 xqb[2], scb[2], shb[2];
    auto ldx = [&](int cc, int slot) {
        int f0 = in_off + cc * 16 + fg * 4;
        scb[slot] = *(const float4*)(scA + f0);
        shb[slot] = *(const float4*)(shA + f0);
        int gn = nblk + n0;
        xqb[slot] = (gn < N) ? *(const float4*)(xc + (size_t)gn * DCAT + f0) : (float4){0.f,0.f,0.f,0.f};
    };

    // W fragments for one chunk, prefetched a chunk ahead
    s16x8 wc_reg[4][2];
    s16x8 wo_reg[4];
    auto loadW = [&](int cc) {
        if (CONV) {
            const unsigned short* wcb = wconv + (size_t)cc * 16384;
#pragma unroll
            for (int kk = 0; kk < 4; ++kk)
#pragma unroll
                for (int c = 0; c < 2; ++c) {
                    int cf = wave * 2 + c;
                    wc_reg[kk][c] = *(const s16x8*)(wcb + (((size_t)kk * 8 + cf) * 64 + lane) * 8);
                }
        }
        const unsigned short* wob = wout + (size_t)cc * 8192;
#pragma unroll
        for (int kk = 0; kk < 4; ++kk)
            wo_reg[kk] = *(const s16x8*)(wob + (((size_t)kk * 4 + wave) * 64 + lane) * 8);
    };

    u16x8 pcur[4];
    auto phi_compute = [&](int ccc, int slot) {
        float xi[4] = {xqb[slot].x, xqb[slot].y, xqb[slot].z, xqb[slot].w};
        float scr[4] = {scb[slot].x, scb[slot].y, scb[slot].z, scb[slot].w};
        float shr[4] = {shb[slot].x, shb[slot].y, shb[slot].z, shb[slot].w};
        u16x4 sv;
#pragma unroll
        for (int fl = 0; fl < 4; ++fl) {
            float y = fmaf(xi[fl], scr[fl], shr[fl]);
            sv[fl] = f2bf_rn(silu_f(y));
            float t = (y - g0) * invh;
            float cf = floorf(t);
            int c = (int)cf;
            float u = t - cf;
            float um = 1.f - u;
            float u2 = u * u;
            float um2 = um * um;
            float w0 = um2 * um * (1.f / 6.f);
            float w3 = u2 * u * (1.f / 6.f);
            float w1 = fmaf(fmaf(0.5f, u, -1.f), u2, 2.f / 3.f);
            float w2 = fmaf(fmaf(-0.5f, u, 0.5f), u2, fmaf(0.5f, u, 1.f / 6.f));
            bool e[11];
#pragma unroll
            for (int v = 0; v < 11; ++v) e[v] = (c == v);
#pragma unroll
            for (int s = 0; s < 8; ++s) {
                float val = 0.f;
                val = e[s] ? w3 : val;
                val = e[s + 1] ? w2 : val;
                val = e[s + 2] ? w1 : val;
                val = e[s + 3] ? w0 : val;
                pcur[fl][s] = f2bf_rn(val);
            }
        }
        int gn = nblk + n0;
        if (gn < N) {
            int fdst = (ccc * 16 + fg * 4) ^ ((n0 & 7) << 3);
            *(u16x4*)(silbuf + (size_t)gn * 128 + fdst) = sv;
        }
    };

    auto write_phi = [&](char* buf) {
        int swz = (n0 & 7) << 4;
#pragma unroll
        for (int i = 0; i < 4; ++i) {
            int byte = n0 * 256 + ((fg * 64 + i * 16) ^ swz);
            *(u16x8*)(buf + byte) = pcur[i];
        }
    };

    auto mfma_phase = [&](const char* buf) {
#pragma unroll
        for (int kk = 0; kk < 4; ++kk) {
            const int kb = kk * 64 + lg * 16;
            s16x8 af[4];
#pragma unroll
            for (int r = 0; r < 4; ++r) {
                int n = r * 16 + l15;
                af[r] = *(const s16x8*)(buf + n * 256 + (kb ^ ((n & 7) << 4)));
            }
            if (CONV) {
#pragma unroll
                for (int c = 0; c < 2; ++c)
#pragma unroll
                    for (int r = 0; r < 4; ++r)
                        accc[r][c] = __builtin_amdgcn_mfma_f32_16x16x32_bf16(af[r], wc_reg[kk][c], accc[r][c], 0, 0, 0);
            }
#pragma unroll
            for (int r = 0; r < 4; ++r)
                acco[r] = __builtin_amdgcn_mfma_f32_16x16x32_bf16(af[r], wo_reg[kk], acco[r], 0, 0, 0);
        }
    };

    // ---- prologue: chunk 0 phi + W(0) + x(1) prefetch ----
    ldx(0, 0);
    phi_compute(0, 0);
    ldx(1, 1);
    loadW(0);
    write_phi(lds_phi0);
    __syncthreads();   // drains W(0)/x loads, phi(0) visible

    // ---- pipelined chunk loop (fully unrolled; one barrier per chunk) ----
#pragma unroll
    for (int cc = 0; cc < 9; ++cc) {
        char* cur = (cc & 1) ? lds_phi1 : lds_phi0;
        char* nxt = (cc & 1) ? lds_phi0 : lds_phi1;
        mfma_phase(cur);
        if (cc < 8) loadW(cc + 1);             // prefetch next chunk's W (regs free after mfma)
        if (cc < 7) {
            ldx(cc + 2, cc & 1);               // x two chunks ahead
            phi_compute(cc + 1, (cc + 1) & 1); // overlaps W-load latency
            write_phi(nxt);
        }
        if (cc == 7) {
            // stage silu chunk (8) from silbuf into lds_phi0
            const unsigned short* ssrc = silbuf + (size_t)nblk * 128;
#pragma unroll
            for (int i = 0; i < 4; ++i) {
                int e = tid + i * 256;
                gload_lds16(ssrc + e * 8, nxt + e * 16);
            }
        }
        if (cc < 8) __syncthreads();
    }

    // epilogue: C row = r*16 + lg*4 + q, conv col = wave*32 + c*16 + l15, out col = wave*16 + l15
#pragma unroll
    for (int r = 0; r < 4; ++r) {
        int nb = nblk + r * 16 + lg * 4;
        if (CONV) {
#pragma unroll
            for (int c = 0; c < 2; ++c) {
                int o = wave * 32 + c * 16 + l15;
#pragma unroll
                for (int q = 0; q < 4; ++q) {
                    int n = nb + q;
                    if (n < N) htmp[(size_t)n * HID + o] = f2bf_rn(accc[r][c][q] * dinv[n]);
                }
            }
        }
        {
            int o = wave * 16 + l15;
            if (o < NCLS) {
#pragma unroll
                for (int q = 0; q < 4; ++q) {
                    int n = nb + q;
                    if (n < N) {
                        size_t a = (size_t)n * OOUT + o;
                        float v = acco[r][q];
                        if (!INIT) v += out_acc[a];
                        out_acc[a] = v;
                    }
                }
            }
        }
    }
}

// ---------------- aggregation (one wave per node; h pre-scaled by dinv) ------
__global__ __launch_bounds__(256) void agg_kernel(const unsigned short* __restrict__ h,
                                                  const float* __restrict__ dinv,
                                                  const int* __restrict__ offs,
                                                  const int* __restrict__ csr,
                                                  const float* __restrict__ bias,
                                                  float* __restrict__ xc, int out_off, int N) {
    int n = blockIdx.x * 4 + (threadIdx.x >> 6);
    if (n >= N) return;
    int lane = threadIdx.x & 63;
    int s = offs[n], e = offs[n + 1];
    float a0 = 0.f, a1 = 0.f, b0 = 0.f, b1 = 0.f;
    float c0 = 0.f, c1 = 0.f, d0 = 0.f, d1 = 0.f;
    int i = s;
    for (; i + 4 <= e; i += 4) {
        int v0 = csr[i], v1 = csr[i + 1], v2 = csr[i + 2], v3 = csr[i + 3];
        unsigned u0 = *(const unsigned*)(h + (size_t)v0 * HID + lane * 2);
        unsigned u1 = *(const unsigned*)(h + (size_t)v1 * HID + lane * 2);
        unsigned u2 = *(const unsigned*)(h + (size_t)v2 * HID + lane * 2);
        unsigned u3 = *(const unsigned*)(h + (size_t)v3 * HID + lane * 2);
        a0 += __uint_as_float(u0 << 16);
        a1 += __uint_as_float(u0 & 0xffff0000u);
        b0 += __uint_as_float(u1 << 16);
        b1 += __uint_as_float(u1 & 0xffff0000u);
        c0 += __uint_as_float(u2 << 16);
        c1 += __uint_as_float(u2 & 0xffff0000u);
        d0 += __uint_as_float(u3 << 16);
        d1 += __uint_as_float(u3 & 0xffff0000u);
    }
    for (; i < e; ++i) {
        int v = csr[i];
        unsigned u = *(const unsigned*)(h + (size_t)v * HID + lane * 2);
        a0 += __uint_as_float(u << 16);
        a1 += __uint_as_float(u & 0xffff0000u);
    }
    a0 += b0 + c0 + d0;
    a1 += b1 + c1 + d1;
    float dn = dinv[n];
    float2 bv = *(const float2*)(bias + lane * 2);
    float2 res = {fmaf(a0, dn, bv.x), fmaf(a1, dn, bv.y)};
    *(float2*)(xc + (size_t)n * DCAT + out_off + lane * 2) = res;
}

// ---------------- batchnorm stats + deferred affine ----------------
__global__ __launch_bounds__(128) void bn_stats_kernel(const float* __restrict__ xc, int off, int N,
                                                       float* __restrict__ bnsum, float* __restrict__ bnsq) {
    int f = threadIdx.x;
    float s = 0.f, q = 0.f;
    for (int n = blockIdx.x; n < N; n += gridDim.x) {
        float v = xc[(size_t)n * DCAT + off + f];
        s += v;
        q += v * v;
    }
    atomicAdd(&bnsum[f], s);
    atomicAdd(&bnsq[f], q);
}

__global__ __launch_bounds__(128) void bn_affine_kernel(const float* __restrict__ bnsum,
                                                        const float* __restrict__ bnsq,
                                                        const float* __restrict__ gamma,
                                                        const float* __restrict__ beta,
                                                        float* scA, float* shA, int seg_off, float invN) {
    int f = threadIdx.x;
    float mu = bnsum[f] * invN;
    float var = bnsq[f] * invN - mu * mu;
    float rs = rsqrtf(var + 1e-5f);
    float s = gamma[f] * rs;
    scA[seg_off + f] = s;
    shA[seg_off + f] = fmaf(-mu, s, beta[f]);
}

// ---------------- log_softmax (thread per node; reads out_acc ld=64) ---------
__global__ __launch_bounds__(256) void logsoftmax_kernel(const float* __restrict__ oacc,
                                                         float* __restrict__ out, int N) {
    for (int n = blockIdx.x * blockDim.x + threadIdx.x; n < N; n += gridDim.x * blockDim.x) {
        const float* row = oacc + (size_t)n * OOUT;
        float m = -1e30f;
#pragma unroll
        for (int j = 0; j < NCLS; ++j) m = fmaxf(m, row[j]);
        float s = 0.f;
#pragma unroll
        for (int j = 0; j < NCLS; ++j) s += __expf(row[j] - m);
        float lse = m + __logf(s);
        float* orow = out + (size_t)n * NCLS;
#pragma unroll
        for (int j = 0; j < NCLS; ++j) orow[j] = row[j] - lse;
    }
}

// ---------------- launch ----------------

extern "C" void kernel_launch(void* const* d_in, const int* in_sizes, int n_in,
                              void* d_out, int out_size, void* d_ws, size_t ws_size,
                              hipStream_t stream) {
    const float* x            = (const float*)d_in[0];
    const int*   eidx         = (const int*)d_in[1];
    const float* conv_base_w  = (const float*)d_in[3];
    const float* conv_spline_w= (const float*)d_in[4];
    const float* conv_scaler  = (const float*)d_in[5];
    const float* conv_bias    = (const float*)d_in[6];
    const float* bn_gamma     = (const float*)d_in[7];
    const float* bn_beta      = (const float*)d_in[8];
    const float* out_base_w   = (const float*)d_in[10];
    const float* out_spline_w = (const float*)d_in[11];
    const float* out_scaler   = (const float*)d_in[12];
    float* out = (float*)d_out;

    int N = in_sizes[0] / F_IN;
    int E = in_sizes[1] / 2;
    const int* esrc = eidx;
    const int* edst = eidx + E;

    int blocks = (N + 63) / 64;
    int npad = blocks * 64;
    int nsb = (N + 255) / 256;

    char* p = (char*)d_ws;
    auto carve = [&](size_t bytes) {
        char* r = p;
        p += (bytes + 255) & ~(size_t)255;
        return r;
    };
    float* xc   = (float*)carve((size_t)N * DCAT * 4);
    unsigned short* htmp = (unsigned short*)carve((size_t)npad * HID * 2);
    float* oacc = (float*)carve((size_t)npad * OOUT * 4);
    unsigned short* silbuf = (unsigned short*)carve((size_t)npad * 128 * 2);
    float* dinv = (float*)carve((size_t)N * 4);
    float* bn   = (float*)carve((size_t)NLAYER * 2 * HID * 4);
    float* scA  = (float*)carve((size_t)DCAT * 4);
    float* shA  = (float*)carve((size_t)DCAT * 4);
    unsigned short* wpkc = (unsigned short*)carve((size_t)NLAYER * 9 * 128 * 128 * 2);
    unsigned short* wpko = (unsigned short*)carve((size_t)36 * 64 * 128 * 2);
    int* deg    = (int*)carve((size_t)N * 4);
    int* offs   = (int*)carve((size_t)(N + 1) * 4);
    int* cursor = (int*)carve((size_t)(N + 1) * 4);
    int* bsum   = (int*)carve((size_t)nsb * 4);
    int* bbase  = (int*)carve((size_t)nsb * 4);
    int* csr    = (int*)carve((size_t)(E + N) * 4);

    hipMemsetAsync(bn, 0, NLAYER * 2 * HID * 4, stream);

    // graph preprocessing
    deg_init_kernel<<<512, 256, 0, stream>>>(deg, N);
    deg_count_kernel<<<1024, 256, 0, stream>>>(edst, E, deg);
    dinv_kernel<<<512, 256, 0, stream>>>(deg, dinv, N);
    scan_reduce_kernel<<<nsb, 256, 0, stream>>>(deg, bsum, N);
    scan_top_kernel<<<1, 256, 0, stream>>>(bsum, bbase, nsb);
    scan_write_kernel<<<nsb, 256, 0, stream>>>(deg, bbase, offs, cursor, N);
    fill_kernel<<<1024, 256, 0, stream>>>(esrc, edst, E, N, cursor, csr);

    // weight packing + x copy + affine init
    pack_conv_mfma<<<1024, 256, 0, stream>>>(conv_base_w, conv_spline_w, conv_scaler, wpkc);
    pack_out_mfma<<<1024, 256, 0, stream>>>(out_base_w, out_spline_w, out_scaler, wpko);
    copyx_kernel<<<2048, 256, 0, stream>>>(x, xc, N);
    affine_init_kernel<<<1, 512, 0, stream>>>(scA, shA);

    float invN = 1.f / (float)N;
    for (int l = 0; l < NLAYER; ++l) {
        int in_off = l * HID;
        int out_off = (l + 1) * HID;
        const unsigned short* wl = wpkc + (size_t)l * 9 * 16384;
        const unsigned short* wo = wpko + (size_t)l * 9 * 8192;
        if (l == 0)
            kan_fused_kernel<true, true><<<blocks, 256, 0, stream>>>(
                xc, in_off, scA, shA, wl, wo, silbuf, htmp, dinv, oacc, N);
        else
            kan_fused_kernel<true, false><<<blocks, 256, 0, stream>>>(
                xc, in_off, scA, shA, wl, wo, silbuf, htmp, dinv, oacc, N);
        agg_kernel<<<(N + 3) / 4, 256, 0, stream>>>(htmp, dinv, offs, csr, conv_bias + l * HID, xc, out_off, N);
        float* bnsum = bn + l * 2 * HID;
        float* bnsq  = bnsum + HID;
        bn_stats_kernel<<<256, 128, 0, stream>>>(xc, out_off, N, bnsum, bnsq);
        bn_affine_kernel<<<1, 128, 0, stream>>>(bnsum, bnsq, bn_gamma + l * HID, bn_beta + l * HID,
                                                scA, shA, out_off, invN);
    }

    // segment 3 (final BN output) -> out partial
    kan_fused_kernel<false, false><<<blocks, 256, 0, stream>>>(
        xc, 384, scA, shA, nullptr, wpko + (size_t)3 * 9 * 8192, silbuf, nullptr, dinv, oacc, N);

    logsoftmax_kernel<<<(N + 255) / 256, 256, 0, stream>>>(oacc, out, N);
}

// Round 12
// 537.256 us; speedup vs baseline: 1.2061x; 1.0153x over previous
//
#include <hip/hip_runtime.h>
#include <hip/hip_bf16.h>
#include <math.h>

#define F_IN   128
#define HID    128
#define NLAYER 3
#define NCLS   40
#define DCAT   512   // F_IN + NLAYER*HID
#define OOUT   64    // padded out-layer cols

typedef short s16x8 __attribute__((ext_vector_type(8)));
typedef unsigned short u16x8 __attribute__((ext_vector_type(8)));
typedef unsigned short u16x4 __attribute__((ext_vector_type(4)));
typedef float f32x4 __attribute__((ext_vector_type(4)));

// ---------------- device helpers ----------------

static __device__ __forceinline__ float silu_f(float x) {
    return x / (1.f + __expf(-x));
}

static __device__ __forceinline__ unsigned short f2bf_rn(float f) {
    union { __hip_bfloat16 h; unsigned short u; } cv;
    cv.h = __float2bfloat16(f);
    return cv.u;
}

// LDS-only barrier: drain ds ops (lgkmcnt) but leave global loads in flight.
static __device__ __forceinline__ void lds_barrier() {
    asm volatile("s_waitcnt lgkmcnt(0)" ::: "memory");
    __builtin_amdgcn_s_barrier();
}

// ---------------- graph preprocessing ----------------

__global__ __launch_bounds__(256) void deg_init_kernel(int* deg, int N) {
    for (int i = blockIdx.x * blockDim.x + threadIdx.x; i < N; i += gridDim.x * blockDim.x)
        deg[i] = 1;  // self-loop
}

__global__ __launch_bounds__(256) void deg_count_kernel(const int* __restrict__ dst, int E, int* deg) {
    for (int i = blockIdx.x * blockDim.x + threadIdx.x; i < E; i += gridDim.x * blockDim.x)
        atomicAdd(&deg[dst[i]], 1);
}

__global__ __launch_bounds__(256) void dinv_kernel(const int* __restrict__ deg, float* dinv, int N) {
    for (int i = blockIdx.x * blockDim.x + threadIdx.x; i < N; i += gridDim.x * blockDim.x)
        dinv[i] = rsqrtf((float)deg[i]);
}

// hierarchical scan: 1 elem/thread, 256/block
__global__ __launch_bounds__(256) void scan_reduce_kernel(const int* __restrict__ deg, int* __restrict__ bsum, int N) {
    __shared__ int sh[256];
    int t = threadIdx.x;
    int e = blockIdx.x * 256 + t;
    sh[t] = (e < N) ? deg[e] : 0;
    __syncthreads();
#pragma unroll
    for (int off = 128; off > 0; off >>= 1) {
        if (t < off) sh[t] += sh[t + off];
        __syncthreads();
    }
    if (t == 0) bsum[blockIdx.x] = sh[0];
}

__global__ __launch_bounds__(256) void scan_top_kernel(const int* __restrict__ bsum, int* __restrict__ bbase, int nsb) {
    __shared__ int sh[256];
    int t = threadIdx.x;
    int chunk = (nsb + 255) >> 8;
    int begin = t * chunk;
    int end = begin + chunk; if (end > nsb) end = nsb;
    int s = 0;
    for (int i = begin; i < end; ++i) s += bsum[i];
    sh[t] = s;
    __syncthreads();
#pragma unroll
    for (int off = 1; off < 256; off <<= 1) {
        int v = 0;
        if (t >= off) v = sh[t - off];
        __syncthreads();
        if (t >= off) sh[t] += v;
        __syncthreads();
    }
    int run = (t == 0) ? 0 : sh[t - 1];
    for (int i = begin; i < end; ++i) {
        bbase[i] = run;
        run += bsum[i];
    }
}

__global__ __launch_bounds__(256) void scan_write_kernel(const int* __restrict__ deg,
                                                         const int* __restrict__ bbase,
                                                         int* __restrict__ offs, int* __restrict__ cursor, int N) {
    __shared__ int sh[256];
    int t = threadIdx.x;
    int e = blockIdx.x * 256 + t;
    int d = (e < N) ? deg[e] : 0;
    sh[t] = d;
    __syncthreads();
#pragma unroll
    for (int off = 1; off < 256; off <<= 1) {
        int v = 0;
        if (t >= off) v = sh[t - off];
        __syncthreads();
        if (t >= off) sh[t] += v;
        __syncthreads();
    }
    int incl = sh[t] + bbase[blockIdx.x];
    int excl = incl - d;
    if (e < N) {
        offs[e] = excl;
        cursor[e] = excl;
        if (e == N - 1) offs[N] = incl;
    }
}

__global__ __launch_bounds__(256) void fill_kernel(const int* __restrict__ src, const int* __restrict__ dst,
                                                   int E, int N, int* cursor, int* __restrict__ csr) {
    int total = E + N;
    for (int i = blockIdx.x * blockDim.x + threadIdx.x; i < total; i += gridDim.x * blockDim.x) {
        if (i < E) {
            int d = dst[i];
            int p = atomicAdd(&cursor[d], 1);
            csr[p] = src[i];
        } else {
            int n = i - E;
            int p = atomicAdd(&cursor[n], 1);
            csr[p] = n;
        }
    }
}

// ---------------- weight packing (bf16, MFMA-fragment order) -----------------
// B-fragment for 16x16x32: lane holds W[o = cf*16 + (lane&15)][k = kk*32 + (lane>>4)*8 + e].
// conv: [l][cc(9)][kk(4)][cf(8)][lane(64)][e(8)]
__global__ __launch_bounds__(256) void pack_conv_mfma(const float* __restrict__ bw,
                                                      const float* __restrict__ sw,
                                                      const float* __restrict__ sc,
                                                      unsigned short* __restrict__ wpk) {
    int total = NLAYER * 9 * 4 * 8 * 64 * 8;
    for (int idx = blockIdx.x * blockDim.x + threadIdx.x; idx < total; idx += gridDim.x * blockDim.x) {
        int e    = idx & 7;
        int lane = (idx >> 3) & 63;
        int cf   = (idx >> 9) & 7;
        int kk   = (idx >> 12) & 3;
        int cc   = (idx >> 14) % 9;
        int l    = idx / (9 << 14);
        int o = cf * 16 + (lane & 15);
        int k = kk * 32 + ((lane >> 4) << 3) + e;
        float v;
        if (cc == 8) {                 // silu chunk
            v = bw[(l * 128 + o) * 128 + k];
        } else {                       // spline chunk: 16 feats x 8 bases
            int f = cc * 16 + (k >> 3);
            int j = k & 7;
            int base = (l * 128 + o) * 128 + f;
            v = sw[base * 8 + j] * sc[base];
        }
        wpk[idx] = f2bf_rn(v);
    }
}

// out: [gcc(36)][kk(4)][cf(4)][lane(64)][e(8)], cols >= NCLS zeroed
__global__ __launch_bounds__(256) void pack_out_mfma(const float* __restrict__ bw,
                                                     const float* __restrict__ sw,
                                                     const float* __restrict__ sc,
                                                     unsigned short* __restrict__ wpk) {
    int total = 36 * 4 * 4 * 64 * 8;
    for (int idx = blockIdx.x * blockDim.x + threadIdx.x; idx < total; idx += gridDim.x * blockDim.x) {
        int e    = idx & 7;
        int lane = (idx >> 3) & 63;
        int cf   = (idx >> 9) & 3;
        int kk   = (idx >> 11) & 3;
        int gcc  = idx >> 13;
        int g = gcc / 9, cc = gcc % 9;
        int o = cf * 16 + (lane & 15);
        int k = kk * 32 + ((lane >> 4) << 3) + e;
        float v = 0.f;
        if (o < NCLS) {
            if (cc == 8) {
                int f = g * 128 + k;
                v = bw[o * DCAT + f];
            } else {
                int f = g * 128 + cc * 16 + (k >> 3);
                int j = k & 7;
                int base = o * DCAT + f;
                v = sw[base * 8 + j] * sc[base];
            }
        }
        wpk[idx] = f2bf_rn(v);
    }
}

// ---------------- misc data movement ----------------

__global__ __launch_bounds__(256) void copyx_kernel(const float* __restrict__ x, float* __restrict__ xc, int N) {
    int total = N * F_IN;
    for (int idx = blockIdx.x * blockDim.x + threadIdx.x; idx < total; idx += gridDim.x * blockDim.x) {
        int n = idx >> 7, f = idx & 127;
        xc[(size_t)n * DCAT + f] = x[idx];
    }
}

__global__ __launch_bounds__(512) void affine_init_kernel(float* scA, float* shA) {
    int i = threadIdx.x;
    scA[i] = 1.f; shA[i] = 0.f;
}

// ---------------- fused KAN GEMM + out-layer partial (bf16 MFMA 16x16x32) ----
// Block: 256 threads (4 waves), tile 64 nodes -> 782 blocks.
// Deep pipeline: phi double-buffered in LDS, ONE lgkm-only barrier/chunk
// (global loads stay in flight across barriers); W fragments prefetched into
// registers one chunk ahead; x prefetched two chunks ahead. Silu values kept
// in registers across chunks 0..7 and written to LDS as chunk 8 (no global
// roundtrip).
template<bool CONV, bool INIT>
__global__ __launch_bounds__(256, 2) void kan_fused_kernel(
    const float* __restrict__ xc, int in_off,
    const float* __restrict__ scA, const float* __restrict__ shA,
    const unsigned short* __restrict__ wconv,
    const unsigned short* __restrict__ wout,
    unsigned short* __restrict__ htmp,
    const float* __restrict__ dinv,
    float* __restrict__ out_acc, int N) {

    __shared__ __align__(16) char lds_phi0[16384];
    __shared__ __align__(16) char lds_phi1[16384];

    const int tid = threadIdx.x;
    const int lane = tid & 63;
    const int wave = tid >> 6;
    const int l15 = lane & 15, lg = lane >> 4;
    const int nblk = blockIdx.x * 64;

    const float g0 = -1.f - 3.f * 0.4f;
    const float invh = 1.f / 0.4f;

    const int fg = tid & 3;
    const int n0 = tid >> 2;   // 0..63

    f32x4 accc[4][2];
    f32x4 acco[4];
    if (CONV) {
#pragma unroll
        for (int r = 0; r < 4; ++r)
#pragma unroll
            for (int c = 0; c < 2; ++c) accc[r][c] = (f32x4)0.f;
    }
#pragma unroll
    for (int r = 0; r < 4; ++r) acco[r] = (f32x4)0.f;

    // double-buffered x/affine (2 chunks ahead)
    float4 xqb[2], scb[2], shb[2];
    auto ldx = [&](int cc, int slot) {
        int f0 = in_off + cc * 16 + fg * 4;
        scb[slot] = *(const float4*)(scA + f0);
        shb[slot] = *(const float4*)(shA + f0);
        int gn = nblk + n0;
        xqb[slot] = (gn < N) ? *(const float4*)(xc + (size_t)gn * DCAT + f0) : (float4){0.f,0.f,0.f,0.f};
    };

    // W fragments for one chunk, prefetched a chunk ahead
    s16x8 wc_reg[4][2];
    s16x8 wo_reg[4];
    auto loadW = [&](int cc) {
        if (CONV) {
            const unsigned short* wcb = wconv + (size_t)cc * 16384;
#pragma unroll
            for (int kk = 0; kk < 4; ++kk)
#pragma unroll
                for (int c = 0; c < 2; ++c) {
                    int cf = wave * 2 + c;
                    wc_reg[kk][c] = *(const s16x8*)(wcb + (((size_t)kk * 8 + cf) * 64 + lane) * 8);
                }
        }
        const unsigned short* wob = wout + (size_t)cc * 8192;
#pragma unroll
        for (int kk = 0; kk < 4; ++kk)
            wo_reg[kk] = *(const s16x8*)(wob + (((size_t)kk * 4 + wave) * 64 + lane) * 8);
    };

    // silu values for chunks 0..7, kept in registers (written as chunk 8)
    u16x4 sreg[8];

    u16x8 pcur[4];
    auto phi_compute = [&](int ccc, int slot) {
        float xi[4] = {xqb[slot].x, xqb[slot].y, xqb[slot].z, xqb[slot].w};
        float scr[4] = {scb[slot].x, scb[slot].y, scb[slot].z, scb[slot].w};
        float shr[4] = {shb[slot].x, shb[slot].y, shb[slot].z, shb[slot].w};
        u16x4 sv;
#pragma unroll
        for (int fl = 0; fl < 4; ++fl) {
            float y = fmaf(xi[fl], scr[fl], shr[fl]);
            sv[fl] = f2bf_rn(silu_f(y));
            float t = (y - g0) * invh;
            float cf = floorf(t);
            int c = (int)cf;
            float u = t - cf;
            float um = 1.f - u;
            float u2 = u * u;
            float um2 = um * um;
            float w0 = um2 * um * (1.f / 6.f);
            float w3 = u2 * u * (1.f / 6.f);
            float w1 = fmaf(fmaf(0.5f, u, -1.f), u2, 2.f / 3.f);
            float w2 = fmaf(fmaf(-0.5f, u, 0.5f), u2, fmaf(0.5f, u, 1.f / 6.f));
            bool e[11];
#pragma unroll
            for (int v = 0; v < 11; ++v) e[v] = (c == v);
#pragma unroll
            for (int s = 0; s < 8; ++s) {
                float val = 0.f;
                val = e[s] ? w3 : val;
                val = e[s + 1] ? w2 : val;
                val = e[s + 2] ? w1 : val;
                val = e[s + 3] ? w0 : val;
                pcur[fl][s] = f2bf_rn(val);
            }
        }
        sreg[ccc] = sv;
    };

    auto write_phi = [&](char* buf) {
        int swz = (n0 & 7) << 4;
#pragma unroll
        for (int i = 0; i < 4; ++i) {
            int byte = n0 * 256 + ((fg * 64 + i * 16) ^ swz);
            *(u16x8*)(buf + byte) = pcur[i];
        }
    };

    // write silu chunk (k = feature index) from sreg into LDS
    auto write_silu = [&](char* buf) {
        int swz = (n0 & 7) << 4;
#pragma unroll
        for (int ccc = 0; ccc < 8; ++ccc) {
            int byte = n0 * 256 + (((ccc * 16 + fg * 4) * 2) ^ swz);
            *(u16x4*)(buf + byte) = sreg[ccc];
        }
    };

    auto mfma_phase = [&](const char* buf) {
#pragma unroll
        for (int kk = 0; kk < 4; ++kk) {
            const int kb = kk * 64 + lg * 16;
            s16x8 af[4];
#pragma unroll
            for (int r = 0; r < 4; ++r) {
                int n = r * 16 + l15;
                af[r] = *(const s16x8*)(buf + n * 256 + (kb ^ ((n & 7) << 4)));
            }
            if (CONV) {
#pragma unroll
                for (int c = 0; c < 2; ++c)
#pragma unroll
                    for (int r = 0; r < 4; ++r)
                        accc[r][c] = __builtin_amdgcn_mfma_f32_16x16x32_bf16(af[r], wc_reg[kk][c], accc[r][c], 0, 0, 0);
            }
#pragma unroll
            for (int r = 0; r < 4; ++r)
                acco[r] = __builtin_amdgcn_mfma_f32_16x16x32_bf16(af[r], wo_reg[kk], acco[r], 0, 0, 0);
        }
    };

    // ---- prologue: chunk 0 phi + W(0) + x(1) prefetch ----
    ldx(0, 0);
    phi_compute(0, 0);
    ldx(1, 1);
    loadW(0);
    write_phi(lds_phi0);
    __syncthreads();   // full drain once

    // ---- pipelined chunk loop (fully unrolled; one lgkm-barrier per chunk) ----
#pragma unroll
    for (int cc = 0; cc < 9; ++cc) {
        char* cur = (cc & 1) ? lds_phi1 : lds_phi0;
        char* nxt = (cc & 1) ? lds_phi0 : lds_phi1;
        if (cc < 7) ldx(cc + 2, cc & 1);       // issue x early (covered by MFMA+phi)
        mfma_phase(cur);
        if (cc < 8) loadW(cc + 1);             // prefetch next chunk's W
        if (cc < 7) {
            phi_compute(cc + 1, (cc + 1) & 1); // overlaps W-load latency
            write_phi(nxt);
        }
        if (cc == 7) write_silu(nxt);          // chunk 8 = silu from registers
        if (cc < 8) lds_barrier();             // ds-drain only; globals stay in flight
    }

    // epilogue: C row = r*16 + lg*4 + q, conv col = wave*32 + c*16 + l15, out col = wave*16 + l15
#pragma unroll
    for (int r = 0; r < 4; ++r) {
        int nb = nblk + r * 16 + lg * 4;
        if (CONV) {
#pragma unroll
            for (int c = 0; c < 2; ++c) {
                int o = wave * 32 + c * 16 + l15;
#pragma unroll
                for (int q = 0; q < 4; ++q) {
                    int n = nb + q;
                    if (n < N) htmp[(size_t)n * HID + o] = f2bf_rn(accc[r][c][q] * dinv[n]);
                }
            }
        }
        {
            int o = wave * 16 + l15;
            if (o < NCLS) {
#pragma unroll
                for (int q = 0; q < 4; ++q) {
                    int n = nb + q;
                    if (n < N) {
                        size_t a = (size_t)n * OOUT + o;
                        float v = acco[r][q];
                        if (!INIT) v += out_acc[a];
                        out_acc[a] = v;
                    }
                }
            }
        }
    }
}

// ---------------- aggregation (one wave per node; h pre-scaled by dinv) ------
__global__ __launch_bounds__(256) void agg_kernel(const unsigned short* __restrict__ h,
                                                  const float* __restrict__ dinv,
                                                  const int* __restrict__ offs,
                                                  const int* __restrict__ csr,
                                                  const float* __restrict__ bias,
                                                  float* __restrict__ xc, int out_off, int N) {
    int n = blockIdx.x * 4 + (threadIdx.x >> 6);
    if (n >= N) return;
    int lane = threadIdx.x & 63;
    int s = offs[n], e = offs[n + 1];
    float a0 = 0.f, a1 = 0.f, b0 = 0.f, b1 = 0.f;
    float c0 = 0.f, c1 = 0.f, d0 = 0.f, d1 = 0.f;
    int i = s;
    for (; i + 4 <= e; i += 4) {
        int v0 = csr[i], v1 = csr[i + 1], v2 = csr[i + 2], v3 = csr[i + 3];
        unsigned u0 = *(const unsigned*)(h + (size_t)v0 * HID + lane * 2);
        unsigned u1 = *(const unsigned*)(h + (size_t)v1 * HID + lane * 2);
        unsigned u2 = *(const unsigned*)(h + (size_t)v2 * HID + lane * 2);
        unsigned u3 = *(const unsigned*)(h + (size_t)v3 * HID + lane * 2);
        a0 += __uint_as_float(u0 << 16);
        a1 += __uint_as_float(u0 & 0xffff0000u);
        b0 += __uint_as_float(u1 << 16);
        b1 += __uint_as_float(u1 & 0xffff0000u);
        c0 += __uint_as_float(u2 << 16);
        c1 += __uint_as_float(u2 & 0xffff0000u);
        d0 += __uint_as_float(u3 << 16);
        d1 += __uint_as_float(u3 & 0xffff0000u);
    }
    for (; i < e; ++i) {
        int v = csr[i];
        unsigned u = *(const unsigned*)(h + (size_t)v * HID + lane * 2);
        a0 += __uint_as_float(u << 16);
        a1 += __uint_as_float(u & 0xffff0000u);
    }
    a0 += b0 + c0 + d0;
    a1 += b1 + c1 + d1;
    float dn = dinv[n];
    float2 bv = *(const float2*)(bias + lane * 2);
    float2 res = {fmaf(a0, dn, bv.x), fmaf(a1, dn, bv.y)};
    *(float2*)(xc + (size_t)n * DCAT + out_off + lane * 2) = res;
}

// ---------------- batchnorm stats + deferred affine ----------------
__global__ __launch_bounds__(128) void bn_stats_kernel(const float* __restrict__ xc, int off, int N,
                                                       float* __restrict__ bnsum, float* __restrict__ bnsq) {
    int f = threadIdx.x;
    float s = 0.f, q = 0.f;
    for (int n = blockIdx.x; n < N; n += gridDim.x) {
        float v = xc[(size_t)n * DCAT + off + f];
        s += v;
        q += v * v;
    }
    atomicAdd(&bnsum[f], s);
    atomicAdd(&bnsq[f], q);
}

__global__ __launch_bounds__(128) void bn_affine_kernel(const float* __restrict__ bnsum,
                                                        const float* __restrict__ bnsq,
                                                        const float* __restrict__ gamma,
                                                        const float* __restrict__ beta,
                                                        float* scA, float* shA, int seg_off, float invN) {
    int f = threadIdx.x;
    float mu = bnsum[f] * invN;
    float var = bnsq[f] * invN - mu * mu;
    float rs = rsqrtf(var + 1e-5f);
    float s = gamma[f] * rs;
    scA[seg_off + f] = s;
    shA[seg_off + f] = fmaf(-mu, s, beta[f]);
}

// ---------------- log_softmax (thread per node; reads out_acc ld=64) ---------
__global__ __launch_bounds__(256) void logsoftmax_kernel(const float* __restrict__ oacc,
                                                         float* __restrict__ out, int N) {
    for (int n = blockIdx.x * blockDim.x + threadIdx.x; n < N; n += gridDim.x * blockDim.x) {
        const float* row = oacc + (size_t)n * OOUT;
        float m = -1e30f;
#pragma unroll
        for (int j = 0; j < NCLS; ++j) m = fmaxf(m, row[j]);
        float s = 0.f;
#pragma unroll
        for (int j = 0; j < NCLS; ++j) s += __expf(row[j] - m);
        float lse = m + __logf(s);
        float* orow = out + (size_t)n * NCLS;
#pragma unroll
        for (int j = 0; j < NCLS; ++j) orow[j] = row[j] - lse;
    }
}

// ---------------- launch ----------------

extern "C" void kernel_launch(void* const* d_in, const int* in_sizes, int n_in,
                              void* d_out, int out_size, void* d_ws, size_t ws_size,
                              hipStream_t stream) {
    const float* x            = (const float*)d_in[0];
    const int*   eidx         = (const int*)d_in[1];
    const float* conv_base_w  = (const float*)d_in[3];
    const float* conv_spline_w= (const float*)d_in[4];
    const float* conv_scaler  = (const float*)d_in[5];
    const float* conv_bias    = (const float*)d_in[6];
    const float* bn_gamma     = (const float*)d_in[7];
    const float* bn_beta      = (const float*)d_in[8];
    const float* out_base_w   = (const float*)d_in[10];
    const float* out_spline_w = (const float*)d_in[11];
    const float* out_scaler   = (const float*)d_in[12];
    float* out = (float*)d_out;

    int N = in_sizes[0] / F_IN;
    int E = in_sizes[1] / 2;
    const int* esrc = eidx;
    const int* edst = eidx + E;

    int blocks = (N + 63) / 64;
    int npad = blocks * 64;
    int nsb = (N + 255) / 256;

    char* p = (char*)d_ws;
    auto carve = [&](size_t bytes) {
        char* r = p;
        p += (bytes + 255) & ~(size_t)255;
        return r;
    };
    float* xc   = (float*)carve((size_t)N * DCAT * 4);
    unsigned short* htmp = (unsigned short*)carve((size_t)npad * HID * 2);
    float* oacc = (float*)carve((size_t)npad * OOUT * 4);
    float* dinv = (float*)carve((size_t)N * 4);
    float* bn   = (float*)carve((size_t)NLAYER * 2 * HID * 4);
    float* scA  = (float*)carve((size_t)DCAT * 4);
    float* shA  = (float*)carve((size_t)DCAT * 4);
    unsigned short* wpkc = (unsigned short*)carve((size_t)NLAYER * 9 * 128 * 128 * 2);
    unsigned short* wpko = (unsigned short*)carve((size_t)36 * 64 * 128 * 2);
    int* deg    = (int*)carve((size_t)N * 4);
    int* offs   = (int*)carve((size_t)(N + 1) * 4);
    int* cursor = (int*)carve((size_t)(N + 1) * 4);
    int* bsum   = (int*)carve((size_t)nsb * 4);
    int* bbase  = (int*)carve((size_t)nsb * 4);
    int* csr    = (int*)carve((size_t)(E + N) * 4);

    hipMemsetAsync(bn, 0, NLAYER * 2 * HID * 4, stream);

    // graph preprocessing
    deg_init_kernel<<<512, 256, 0, stream>>>(deg, N);
    deg_count_kernel<<<1024, 256, 0, stream>>>(edst, E, deg);
    dinv_kernel<<<512, 256, 0, stream>>>(deg, dinv, N);
    scan_reduce_kernel<<<nsb, 256, 0, stream>>>(deg, bsum, N);
    scan_top_kernel<<<1, 256, 0, stream>>>(bsum, bbase, nsb);
    scan_write_kernel<<<nsb, 256, 0, stream>>>(deg, bbase, offs, cursor, N);
    fill_kernel<<<1024, 256, 0, stream>>>(esrc, edst, E, N, cursor, csr);

    // weight packing + x copy + affine init
    pack_conv_mfma<<<1024, 256, 0, stream>>>(conv_base_w, conv_spline_w, conv_scaler, wpkc);
    pack_out_mfma<<<1024, 256, 0, stream>>>(out_base_w, out_spline_w, out_scaler, wpko);
    copyx_kernel<<<2048, 256, 0, stream>>>(x, xc, N);
    affine_init_kernel<<<1, 512, 0, stream>>>(scA, shA);

    float invN = 1.f / (float)N;
    for (int l = 0; l < NLAYER; ++l) {
        int in_off = l * HID;
        int out_off = (l + 1) * HID;
        const unsigned short* wl = wpkc + (size_t)l * 9 * 16384;
        const unsigned short* wo = wpko + (size_t)l * 9 * 8192;
        if (l == 0)
            kan_fused_kernel<true, true><<<blocks, 256, 0, stream>>>(
                xc, in_off, scA, shA, wl, wo, htmp, dinv, oacc, N);
        else
            kan_fused_kernel<true, false><<<blocks, 256, 0, stream>>>(
                xc, in_off, scA, shA, wl, wo, htmp, dinv, oacc, N);
        agg_kernel<<<(N + 3) / 4, 256, 0, stream>>>(htmp, dinv, offs, csr, conv_bias + l * HID, xc, out_off, N);
        float* bnsum = bn + l * 2 * HID;
        float* bnsq  = bnsum + HID;
        bn_stats_kernel<<<256, 128, 0, stream>>>(xc, out_off, N, bnsum, bnsq);
        bn_affine_kernel<<<1, 128, 0, stream>>>(bnsum, bnsq, bn_gamma + l * HID, bn_beta + l * HID,
                                                scA, shA, out_off, invN);
    }

    // segment 3 (final BN output) -> out partial
    kan_fused_kernel<false, false><<<blocks, 256, 0, stream>>>(
        xc, 384, scA, shA, nullptr, wpko + (size_t)3 * 9 * 8192, htmp, dinv, oacc, N);

    logsoftmax_kernel<<<(N + 255) / 256, 256, 0, stream>>>(oacc, out, N);
}